// Round 11
// baseline (297.619 us; speedup 1.0000x reference)
//
#include <hip/hip_runtime.h>
#include <math.h>

// ---------------------------------------------------------------------------
// PAE pipeline on MI355X. Round 24:
//   k_prefix_ln: round-23 concept (full R tile in LDS, no global R
//           round-trip) re-issued UNDER the hardware-proven 128 KiB LDS
//           envelope: stage buffer [240][65] -> [240][17] ushort, 8 chunks
//           of 16 cols. Total LDS 125,280 B (was 148,320 -- the suspected
//           cause of round-23's container failure; largest verified
//           workgroup LDS on MI355X is 128 KiB). h3 output bit-identical
//           (same bf16 round-trip). Dispatch traffic 141 -> 74 MB.
//   Everything else byte-identical to round 22 (262.7us verified).
// ---------------------------------------------------------------------------

#define INCH   72
#define TLEN   121
#define FULL   240
#define INTER  24
#define EMB    8
#define LP     360
#define NWIN   3840

typedef __attribute__((ext_vector_type(8)))  short s16x8;
typedef __attribute__((ext_vector_type(4)))  float f32x4;

__device__ __forceinline__ unsigned short f2bf(float f) {
    unsigned u = __float_as_uint(f);
    unsigned r = ((u >> 16) & 1u) + 0x7FFFu;
    return (unsigned short)((u + r) >> 16);
}
__device__ __forceinline__ float bf2f(unsigned short u) {
    return __uint_as_float((unsigned)u << 16);
}

// ---------------------------------------------------------------------------
// k_prep_all: w2f | w3f | w1fA in one launch. (round 17: w2f padded to 64)
// ---------------------------------------------------------------------------
__global__ __launch_bounds__(256) void k_prep_all(
    const float* __restrict__ w2, const float* __restrict__ w1,
    short* __restrict__ w2f, short* __restrict__ w3f, short* __restrict__ w1fA)
{
    int gid = blockIdx.x * 256 + threadIdx.x;
    if (gid < 32768) {                                   // w2f (packed pairs, 64 frags)
        int idx = gid;
        int j = idx & 7, ln = (idx >> 3) & 63, s = idx >> 9;   // s 0..63
        int nn = ln & 15, c = (ln >> 4) * 8 + j;
        int e = nn & 7;
        int tap = 2 * s + (nn >> 3);
        float v = (c < INTER && tap <= 120) ? w2[(e * INTER + c) * TLEN + tap] : 0.0f;
        w2f[idx] = (short)f2bf(v);
    } else if (gid < 49152) {                            // w3f
        int idx = gid - 32768;
        int j = idx & 7, ln = (idx >> 3) & 63, tl = (idx >> 9) & 7, ch = idx >> 12;
        int t = (ln >> 4) * 8 + j + ch * 32;
        int colIdx = (tl & 3) * 16 + (ln & 15);
        int k = colIdx + 1;
        float v = 0.0f;
        if (t < TLEN && colIdx < 60) {
            int mm = (k * t) % 121;
            float s, c;
            sincosf(6.2831853071795864f * (float)mm / 121.0f, &s, &c);
            v = (tl < 4) ? c : -s;
        }
        w3f[idx] = (short)f2bf(v);
    } else if (gid < 420864) {                           // w1fA
        int idx = gid - 49152;
        int j = idx & 7, ln = (idx >> 3) & 63;
        int rest = idx >> 9;
        int ch = rest % 3;
        int rest2 = rest / 3;
        int ot = rest2 & 1, tap = rest2 >> 1;
        int o = ot * 16 + (ln & 15);
        int c = (ln >> 4) * 8 + j + ch * 32;
        float v = (o < INTER && c < INCH) ? w1[(o * INCH + c) * TLEN + tap] : 0.0f;
        w1fA[idx] = (short)f2bf(v);
    }
}

// ---------------------------------------------------------------------------
// k_prep_dec: bf16 MFMA fragments for the decoder convs. (round 15)
// ---------------------------------------------------------------------------
__global__ __launch_bounds__(256) void k_prep_dec(
    const float* __restrict__ dw1, const float* __restrict__ dw2,
    short* __restrict__ w1D, short* __restrict__ w2D)
{
    int gid = blockIdx.x * 256 + threadIdx.x;
    if (gid < 309760) {                                  // w2D
        int j = gid & 7, lane = (gid >> 3) & 63;
        int rest = gid >> 9;                             // m*5 + octile
        int ot = rest % 5, m = rest / 5;
        int oc = ot * 16 + (lane & 15);
        int c  = (lane >> 4) * 8 + j;
        float v = (oc < INCH && c < INTER) ? dw2[(oc * INTER + c) * TLEN + m] : 0.0f;
        w2D[gid] = (short)f2bf(v);
    } else if (gid < 341504) {                           // w1D
        int idx = gid - 309760;
        int j = idx & 7, lane = (idx >> 3) & 63;
        int rest = idx >> 9;                             // st*2 + octile
        int ot = rest & 1, st = rest >> 1;
        int oc = ot * 16 + (lane & 15);
        int m  = st * 4 + (lane >> 4);
        float v = (oc < INTER && m < TLEN) ? dw1[(oc * EMB + j) * TLEN + m] : 0.0f;
        w1D[idx] = (short)f2bf(v);
    }
}

// ---------------------------------------------------------------------------
// k_q: Q[b][o][m][s] = sum_c w1[o,c,m] * x[b,c,(s+m)%240] via MFMA.
// Round 22: swapped operands (A = x rows=s, B = w1 cols=o) -> float4 stores;
// grid 512 (16 m-groups of 8 taps) -> 2 blocks/CU.
// ---------------------------------------------------------------------------
__global__ __launch_bounds__(256) void k_q(
    const float* __restrict__ x, const short* __restrict__ w1fA,
    float* __restrict__ Q)
{
    const int blk = blockIdx.x;
    const int mg2 = blk & 15, sh = (blk >> 4) & 1, b = blk >> 5;
    const int tid = threadIdx.x;
    const int lane = tid & 63, wid = tid >> 6;
    const int s0 = sh * 120;
    __shared__ __align__(16) short xTb[248 * 104];   // 51584 B

    for (int idx = tid; idx < (248 * 104) / 8; idx += 256)
        ((uint4*)xTb)[idx] = make_uint4(0, 0, 0, 0);
    __syncthreads();
    for (int idx = tid; idx < 72 * 248; idx += 256) {
        int c = idx / 248, l = idx - c * 248;
        int g = s0 + l; g -= (g >= FULL) ? FULL : 0;
        xTb[l * 104 + c] = (short)f2bf(x[(b * INCH + c) * FULL + g]);
    }
    __syncthreads();

    const int ntaps = (mg2 < 15) ? 8 : 1;            // taps 120 only in group 15
    const int m16 = lane & 15, quad = lane >> 4;
    for (int j = 0; j < ntaps; ++j) {
        const int m = mg2 * 8 + j;
        s16x8 bw[2][3];                              // w1 B-fragments (cols=o)
#pragma unroll
        for (int ot = 0; ot < 2; ++ot)
#pragma unroll
            for (int ch = 0; ch < 3; ++ch)
                bw[ot][ch] = *(const s16x8*)(w1fA + (((m * 2 + ot) * 3 + ch) * 64 + lane) * 8);
#pragma unroll
        for (int tt = 0; tt < 2; ++tt) {
            const int ts = (wid + tt * 4) * 16;      // s-tile base
            const short* arow = xTb + (ts + m16 + m) * 104 + quad * 8;
            s16x8 a0 = *(const s16x8*)(arow);        // A rows = s, k = c
            s16x8 a1 = *(const s16x8*)(arow + 32);
            s16x8 a2 = *(const s16x8*)(arow + 64);
#pragma unroll
            for (int ot = 0; ot < 2; ++ot) {
                f32x4 acc = {0.0f, 0.0f, 0.0f, 0.0f};
                acc = __builtin_amdgcn_mfma_f32_16x16x32_bf16(a0, bw[ot][0], acc, 0, 0, 0);
                acc = __builtin_amdgcn_mfma_f32_16x16x32_bf16(a1, bw[ot][1], acc, 0, 0, 0);
                acc = __builtin_amdgcn_mfma_f32_16x16x32_bf16(a2, bw[ot][2], acc, 0, 0, 0);
                const int o = ot * 16 + m16;         // C col = o
                if (o < INTER) {
                    const int sbase = ts + quad * 4; // C row = s
                    float* qp = Q + ((size_t)(b * INTER + o) * TLEN + m) * FULL + s0 + sbase;
                    if (sbase + 3 < 120) {
                        *(float4*)qp = make_float4(acc[0], acc[1], acc[2], acc[3]);
                    } else {
#pragma unroll
                        for (int r = 0; r < 4; ++r)
                            if (sbase + r < 120) qp[r] = acc[r];
                    }
                }
            }
        }
    }
}

// ---------------------------------------------------------------------------
// k_prefix_ln: fused prefix + conv1-diff + LN + tanh -> bf16 h3 overlay.
// Round 24: full R tile in LDS (no global R round-trip). Rlds[121][240] fp32
// + r121s + chunked stage[240][17] ushort = 125,280 B (< proven 128 KiB).
// Pass-2 recomputes v from LDS with the r21 bf16 round-trip -> bit-identical.
// Dump: [240][128] zero-padded ushort rows (coalesced uint4) for k_enc2,
// 8 chunks of 16 cols.
// ---------------------------------------------------------------------------
__global__ __launch_bounds__(256, 1) void k_prefix_ln(
    float* __restrict__ Q, const float* __restrict__ b1,
    const float* __restrict__ lna, const float* __restrict__ lnb)
{
    const int blk = blockIdx.x;          // b*24 + o
    const int o = blk % INTER;
    const int tid = threadIdx.x;
    __shared__ __align__(16) float Rlds[TLEN * FULL];         // 116160 B
    __shared__ float r121s[FULL];                             // 960 B
    __shared__ __align__(16) unsigned short stage[FULL * 17]; // 8160 B
    float* Rg = Q + (size_t)blk * (TLEN * FULL);

    // load Q tile into LDS (fully coalesced float4; no write-back ever)
    for (int idx = tid; idx < (TLEN * FULL) / 4; idx += 256)
        ((float4*)Rlds)[idx] = ((const float4*)Rg)[idx];
    __syncthreads();

    // prefix over taps in LDS, col = tid (lane-consecutive cols: 2-way free)
    if (tid < FULL) {
        float* Qc = Rlds + tid;
        float P = 0.0f;
        for (int m = 0; m < TLEN; ++m) {
            P += Qc[m * FULL];
            Qc[m * FULL] = P;
        }
        r121s[tid] = P;
    }
    __syncthreads();

    // pass 1: stats only (same i order / arithmetic as round 21)
    const float bias = b1[o];
    float mean = 0.0f, inv = 0.0f;
    if (tid < FULL) {
        const int n = tid;
        float s = 0.0f, s2 = 0.0f;
        for (int i = 0; i < 60; ++i) {
            int st = n + i - 120; st += (st < 0) ? FULL : 0;
            float v = r121s[st] - Rlds[(59 - i) * FULL + st] + bias;
            s += v; s2 += v * v;
        }
        {
            int st = n - 60; st += (st < 0) ? FULL : 0;
            float v = r121s[st] + bias;
            s += v; s2 += v * v;
        }
        for (int i = 61; i < TLEN; ++i) {
            int st = n + i - 120; st += (st < 0) ? FULL : 0;
            float v = Rlds[(180 - i) * FULL + st] + bias;
            s += v; s2 += v * v;
        }
        mean = s * (1.0f / 121.0f);
        float var = fmaxf((s2 - s * mean) * (1.0f / 120.0f), 0.0f);    // ddof=1
        inv = 1.0f / (sqrtf(var) + 1e-5f);                             // (std+eps)
    }

    // pass 2: recompute v, transform+tanh, stage 16-col chunks, dump coalesced
    unsigned short* dstg = (unsigned short*)Rg;
    for (int ch = 0; ch < 8; ++ch) {
        if (tid < FULL) {
            const int n = tid;
            unsigned short* srow = stage + n * 17;
            for (int k = 0; k < 16; ++k) {
                const int i = ch * 16 + k;
                unsigned short hv = 0;
                if (i < TLEN) {
                    int st = n + i - 120; st += (st < 0) ? FULL : 0;
                    float v;
                    if (i < 60)       v = r121s[st] - Rlds[(59 - i) * FULL + st] + bias;
                    else if (i == 60) v = r121s[st] + bias;
                    else              v = Rlds[(180 - i) * FULL + st] + bias;
                    v = bf2f(f2bf(v));               // match r21's bf16 round-trip
                    v = (v - mean) * inv * lna[i] + lnb[i];
                    hv = f2bf(tanhf(v));
                }
                srow[k] = hv;
            }
        }
        __syncthreads();
        for (int idx = tid; idx < 480; idx += 256) {
            int row = idx >> 1, q = idx & 1;
            const unsigned short* src = stage + row * 17 + q * 8;
            uint4 v;
            v.x = (unsigned)src[0] | ((unsigned)src[1] << 16);
            v.y = (unsigned)src[2] | ((unsigned)src[3] << 16);
            v.z = (unsigned)src[4] | ((unsigned)src[5] << 16);
            v.w = (unsigned)src[6] | ((unsigned)src[7] << 16);
            *(uint4*)(dstg + row * 128 + ch * 16 + q * 8) = v;
        }
        __syncthreads();
    }
}

// ---------------------------------------------------------------------------
// enc2 epilogue (verified round-18 code, per window). Caller must have
// synced; overlay buffers live in hTA. Trailing sync included.
// ---------------------------------------------------------------------------
__device__ __forceinline__ void enc2_epilogue(
    f32x4 acc0, f32x4 acc1, int gwin, int nwin, int b,
    int tid, int lane, int wid,
    float* latf, short* latb, float* S0, float* S1, float* vv, float* bm,
    const short* __restrict__ w3f, const float* __restrict__ b2,
    const float* __restrict__ fcw, const float* __restrict__ fcb,
    float* __restrict__ pP, float* __restrict__ pF,
    float* __restrict__ pA, float* __restrict__ pB,
    float* __restrict__ oLat, float* __restrict__ oP, float* __restrict__ oF,
    float* __restrict__ oA, float* __restrict__ oB)
{
    const int m16 = lane & 15, quad = lane >> 4;
    const int t0 = wid * 32;

    // E pass (cols 0..7): plain stores cover latf[e][0..127]
    if (m16 < 8) {
#pragma unroll
        for (int r = 0; r < 4; ++r) {
            latf[m16 * 132 + t0 +      quad * 4 + r] = acc0[r];
            latf[m16 * 132 + t0 + 16 + quad * 4 + r] = acc1[r];
        }
    }
    if (tid < 8) { S0[tid] = 0.0f; S1[tid] = 0.0f; }
    if (tid < 64) {                                  // latb pad cols 121..127 = 0
        int e_ = tid >> 3, i = 121 + (tid & 7);
        if (i < 128) latb[e_ * 136 + i] = 0;
    }
    __syncthreads();
    // O pass (cols 8..15): accumulate at i-1 (distinct (e,i) per lane)
    if (m16 >= 8) {
        const int e_ = m16 - 8;
#pragma unroll
        for (int r = 0; r < 4; ++r) {
            int i0 = t0 + quad * 4 + r - 1;
            if (i0 >= 0) latf[e_ * 132 + i0] += acc0[r];
            latf[e_ * 132 + t0 + 15 + quad * 4 + r] += acc1[r];
        }
    }
    __syncthreads();
    // bias + bf16 mirror
    for (int idx = tid; idx < EMB * TLEN; idx += 256) {
        int e_ = idx / TLEN, i = idx - e_ * TLEN;
        float v = latf[e_ * 132 + i] + b2[e_];
        latf[e_ * 132 + i] = v;
        latb[e_ * 136 + i] = (short)f2bf(v);
    }
    __syncthreads();

    // --- DFT via MFMA (lanes e>=8 feed zero A rows) ---
    {
        f32x4 accR = {0,0,0,0};
        f32x4 accI = {0,0,0,0};
#pragma unroll
        for (int ch = 0; ch < 4; ++ch) {
            s16x8 afr = {0,0,0,0,0,0,0,0};
            if (m16 < 8) afr = *(const s16x8*)(latb + m16 * 136 + quad * 8 + ch * 32);
            s16x8 br = *(const s16x8*)(w3f + (((ch * 8) + wid) * 64 + lane) * 8);
            s16x8 bi = *(const s16x8*)(w3f + (((ch * 8) + 4 + wid) * 64 + lane) * 8);
            accR = __builtin_amdgcn_mfma_f32_16x16x32_bf16(afr, br, accR, 0, 0, 0);
            accI = __builtin_amdgcn_mfma_f32_16x16x32_bf16(afr, bi, accI, 0, 0, 0);
        }
        const int colj = m16;
        const int col  = wid * 16 + colj;
        const float fw = 0.5f * (float)(col + 1);
#pragma unroll
        for (int r = 0; r < 4; ++r) {
            float pw = (col < 60) ? (accR[r] * accR[r] + accI[r] * accI[r]) : 0.0f;
            float s1 = pw * fw;
#pragma unroll
            for (int off = 1; off < 16; off <<= 1) {
                pw += __shfl_xor(pw, off);
                s1 += __shfl_xor(s1, off);
            }
            if (colj == 0) {
                int e = quad * 4 + r;
                if (e < EMB) { atomicAdd(&S0[e], pw); atomicAdd(&S1[e], s1); }
            }
        }
    }
    // --- fc (threads 0..127) + channel means (128..191), 8-lane reductions ---
    if (tid < 128) {
        const int outi = tid >> 3, l8 = tid & 7;
        const int e_ = outi >> 1;
        const float* fr = fcw + outi * TLEN;
        float av = 0.0f;
        for (int t = l8; t < TLEN; t += 8) av += latf[e_ * 132 + t] * fr[t];
        av += __shfl_xor(av, 1); av += __shfl_xor(av, 2); av += __shfl_xor(av, 4);
        if (l8 == 0) vv[outi] = fcb[outi] + av;
    } else if (tid < 192) {
        const int idx2 = tid - 128;
        const int e_ = idx2 >> 3, l8 = idx2 & 7;
        float ssum = 0.0f;
        for (int t = l8; t < TLEN; t += 8) ssum += latf[e_ * 132 + t];
        ssum += __shfl_xor(ssum, 1); ssum += __shfl_xor(ssum, 2); ssum += __shfl_xor(ssum, 4);
        if (l8 == 0) bm[e_] = ssum * (1.0f / 121.0f);
    }
    __syncthreads();

    if (tid < 8) {
        int e_ = tid;
        float fv = S1[e_] / S0[e_];
        float av = 2.0f * sqrtf(S0[e_]) * (1.0f / 121.0f);
        float pv = atan2f(vv[2 * e_ + 1], vv[2 * e_]) * 0.15915494309189535f;
        float bv = bm[e_];
        int gi = gwin * 8 + e_;
        pP[gi] = pv; pF[gi] = fv; pA[gi] = av; pB[gi] = bv;
        if (nwin == 0) {
            oP[b * 8 + e_] = pv;
            oF[b * 8 + e_] = fv;
            oA[b * 8 + e_] = av;
            oB[b * 8 + e_] = bv;
        }
    }
    if (nwin == 0) {
        for (int idx = tid; idx < EMB * TLEN; idx += 256) {
            int e_ = idx / TLEN, i = idx - e_ * TLEN;
            oLat[(b * EMB + e_) * TLEN + i] = latf[e_ * 132 + i];
        }
    }
    __syncthreads();    // next window's epilogue reuses the overlay buffers
}

// ---------------------------------------------------------------------------
// k_enc2: 2-window conv2 MFMA (shared w2f B-fragments) + per-window epilogue.
// Block = (b, nb) -> windows {2nb, 2nb+1}. Grid 1920. (round 20)
// ---------------------------------------------------------------------------
__global__ __launch_bounds__(256, 4) void k_enc2(
    const float* __restrict__ Q, const short* __restrict__ w2f,
    const short* __restrict__ w3f, const float* __restrict__ b2,
    const float* __restrict__ fcw, const float* __restrict__ fcb,
    float* __restrict__ pP, float* __restrict__ pF, float* __restrict__ pA, float* __restrict__ pB,
    float* __restrict__ oLat, float* __restrict__ oP, float* __restrict__ oF,
    float* __restrict__ oA, float* __restrict__ oB)
{
    const int blk = blockIdx.x;          // b*120 + nb
    const int b   = blk / 120, nb = blk - b * 120;
    const int nA  = 2 * nb, nB = 2 * nb + 1;
    const int tid = threadIdx.x;
    const int lane = tid & 63, wid = tid >> 6;

    __shared__ __align__(16) short hTA[248 * 40];    // 19840 B
    __shared__ __align__(16) short hTB[248 * 40];    // 19840 B
    // epilogue overlay on hTA (dead after conv loop):
    float* latf = (float*)hTA;                       // [EMB*132]  4224 B
    short* latb = (short*)((char*)hTA + 4224);       // [EMB*136]  2176 B
    float* S0   = (float*)((char*)hTA + 6400);       // [8]
    float* S1   = (float*)((char*)hTA + 6432);       // [8]
    float* vv   = (float*)((char*)hTA + 6464);       // [16]
    float* bm   = (float*)((char*)hTA + 6528);       // [8]

    for (int idx = tid; idx < 1240; idx += 256) {
        ((uint4*)hTA)[idx] = make_uint4(0,0,0,0);
        ((uint4*)hTB)[idx] = make_uint4(0,0,0,0);
    }
    __syncthreads();

    // staging: coalesced uint4 loads of 128-short-aligned h3 rows, transposed
    // scatter into hT[(60+i)][o]. 768 = 2 windows x 24 ch x 16 uint4.
    for (int idx = tid; idx < 768; idx += 256) {
        int win = (idx >= 384);
        int rem = idx - win * 384;
        int o = rem >> 4, u4 = rem & 15;
        const unsigned short* h3 =
            (const unsigned short*)(Q + (size_t)(b * INTER + o) * (TLEN * FULL));
        uint4 v = *(const uint4*)(h3 + (win ? nB : nA) * 128 + u4 * 8);
        short* hX = win ? hTB : hTA;
        int rbase = (60 + u4 * 8) * 40 + o;
        hX[rbase +   0] = (short)(v.x & 0xFFFF);
        hX[rbase +  40] = (short)(v.x >> 16);
        hX[rbase +  80] = (short)(v.y & 0xFFFF);
        hX[rbase + 120] = (short)(v.y >> 16);
        hX[rbase + 160] = (short)(v.z & 0xFFFF);
        hX[rbase + 200] = (short)(v.z >> 16);
        hX[rbase + 240] = (short)(v.w & 0xFFFF);
        hX[rbase + 280] = (short)(v.w >> 16);
    }
    __syncthreads();

    const int m16 = lane & 15, quad = lane >> 4;
    const int t0 = wid * 32;

    // --- conv2 MFMA: packed tap pairs, 61 steps, 2 windows share bw ---
    f32x4 accA0 = {0,0,0,0}, accA1 = {0,0,0,0};
    f32x4 accB0 = {0,0,0,0}, accB1 = {0,0,0,0};
    const short* aptrA = hTA + (t0 + m16) * 40 + quad * 8;
    const short* aptrB = hTB + (t0 + m16) * 40 + quad * 8;
    s16x8 ringA[8], ringB[8];
#pragma unroll
    for (int j = 0; j < 8; ++j) {
        ringA[j] = *(const s16x8*)(aptrA + 2 * j * 40);
        ringB[j] = *(const s16x8*)(aptrB + 2 * j * 40);
    }
#pragma unroll
    for (int s = 0; s < 61; ++s) {
        const int k = s & 7;
        s16x8 bw  = *(const s16x8*)(w2f + s * 512 + lane * 8);
        s16x8 nwA = *(const s16x8*)(aptrA + (2 * s + 16) * 40);
        s16x8 nwB = *(const s16x8*)(aptrB + (2 * s + 16) * 40);
        accA0 = __builtin_amdgcn_mfma_f32_16x16x32_bf16(ringA[k], bw, accA0, 0, 0, 0);
        accA1 = __builtin_amdgcn_mfma_f32_16x16x32_bf16(nwA,      bw, accA1, 0, 0, 0);
        accB0 = __builtin_amdgcn_mfma_f32_16x16x32_bf16(ringB[k], bw, accB0, 0, 0, 0);
        accB1 = __builtin_amdgcn_mfma_f32_16x16x32_bf16(nwB,      bw, accB1, 0, 0, 0);
        ringA[k] = nwA;
        ringB[k] = nwB;
    }
    __syncthreads();   // hTA dead from here; overlay live

    enc2_epilogue(accA0, accA1, b * FULL + nA, nA, b, tid, lane, wid,
                  latf, latb, S0, S1, vv, bm, w3f, b2, fcw, fcb,
                  pP, pF, pA, pB, oLat, oP, oF, oA, oB);
    enc2_epilogue(accB0, accB1, b * FULL + nB, nB, b, tid, lane, wid,
                  latf, latb, S0, S1, vv, bm, w3f, b2, fcw, fcb,
                  pP, pF, pA, pB, oLat, oP, oF, oA, oB);
}

// ---------------------------------------------------------------------------
// k_signal: sinusoid resynthesis + overlap-add, gather form. (round 18)
// ---------------------------------------------------------------------------
__global__ __launch_bounds__(256) void k_signal(
    const float* __restrict__ pP, const float* __restrict__ pF,
    const float* __restrict__ pA, const float* __restrict__ pB,
    float* __restrict__ sig, float* __restrict__ oSig)
{
    const int blk = blockIdx.x;          // (b*8 + e)*3 + uc
    const int uc = blk % 3;
    const int be = blk / 3;
    const int b = be >> 3, e = be & 7;
    const int tid = threadIdx.x;
    __shared__ float sp[FULL], sf[FULL], sa[FULL], sb[FULL];
    for (int nn = tid; nn < FULL; nn += 256) {
        int gi = (b * FULL + nn) * 8 + e;
        sp[nn] = pP[gi]; sf[nn] = pF[gi]; sa[nn] = pA[gi]; sb[nn] = pB[gi];
    }
    __syncthreads();
    if (tid < 240) {
        const int u = uc * 120 + (tid >> 1);
        const int half = tid & 1;
        int nlo = (u - 120 > 0) ? (u - 120) : 0;
        int nhi = (u < 239) ? u : 239;
        int mid = (nlo + nhi + 1) >> 1;
        int lo = half ? mid : nlo;
        int hi = half ? nhi : (mid - 1);
        float s = 0.0f;
        for (int nn = lo; nn <= hi; ++nn) {
            float tt = (float)(u - nn);
            float z = sf[nn] * (tt * (1.0f / 60.0f) - 1.0f) + sp[nn];
            z -= floorf(z);
            s += sa[nn] * sinf(6.2831853071795864f * z) + sb[nn];
        }
        s += __shfl_xor(s, 1);
        if (half == 0) {
            float wgt = (u < TLEN) ? (float)(u + 1) : ((u > 239) ? (float)(LP - u) : 121.0f);
            float val = s / wgt;
            sig[(b * EMB + e) * LP + u] = val;
            if (u < TLEN) oSig[(b * EMB + e) * TLEN + u] = val;
        }
    }
}

// ---------------------------------------------------------------------------
// k_dec1: decoder conv1 via MFMA. Block = (b, shalf) = 32 blocks. (round 15)
// ---------------------------------------------------------------------------
__global__ __launch_bounds__(256) void k_dec1(
    const float* __restrict__ sig, const short* __restrict__ w1D, const float* __restrict__ db1,
    float* __restrict__ dbuf, float* __restrict__ bns)
{
    const int blk = blockIdx.x;            // b*2 + shalf
    const int shalf = blk & 1, b = blk >> 1;
    const int tid = threadIdx.x;
    const int lane = tid & 63, wid = tid >> 6;
    __shared__ __align__(16) short yT[256 * 8];      // 4096 B (rows 248..255 stay 0)
    __shared__ float sS[INTER], sS2[INTER];

    if (tid < 256) ((uint4*)yT)[tid] = make_uint4(0, 0, 0, 0);
    if (tid < INTER) { sS[tid] = 0.0f; sS2[tid] = 0.0f; }
    __syncthreads();
    const int qbase = shalf * 120 - 60;
    for (int idx = tid; idx < 248 * 8; idx += 256) {
        int c = idx / 248, pos = idx - c * 248;
        int qy = qbase + pos;
        if (qy >= 0 && qy < FULL)
            yT[pos * 8 + c] = (short)f2bf(sig[(b * EMB + c) * LP + qy + 60]);
    }
    __syncthreads();

    const int col = lane & 15, quad = lane >> 4;
    f32x4 aA0 = {0,0,0,0}, aA1 = {0,0,0,0};   // stile wid   x octile 0/1
    f32x4 aB0 = {0,0,0,0}, aB1 = {0,0,0,0};   // stile wid+4 x octile 0/1
    const short* bb0 = yT + (wid * 16 + col + quad) * 8;
    const short* bb1 = yT + ((wid + 4) * 16 + col + quad) * 8;
#pragma unroll 4
    for (int st = 0; st < 31; ++st) {
        s16x8 a0 = *(const s16x8*)(w1D + ((st * 2 + 0) * 64 + lane) * 8);
        s16x8 a1 = *(const s16x8*)(w1D + ((st * 2 + 1) * 64 + lane) * 8);
        s16x8 b0 = *(const s16x8*)(bb0 + st * 32);
        s16x8 b1 = *(const s16x8*)(bb1 + st * 32);
        aA0 = __builtin_amdgcn_mfma_f32_16x16x32_bf16(a0, b0, aA0, 0, 0, 0);
        aA1 = __builtin_amdgcn_mfma_f32_16x16x32_bf16(a1, b0, aA1, 0, 0, 0);
        aB0 = __builtin_amdgcn_mfma_f32_16x16x32_bf16(a0, b1, aB0, 0, 0, 0);
        aB1 = __builtin_amdgcn_mfma_f32_16x16x32_bf16(a1, b1, aB1, 0, 0, 0);
    }

    // epilogue: bias + store dbuf + masked stats (col-reduce then LDS atomics)
#pragma unroll
    for (int half = 0; half < 2; ++half) {
        const int sl_base = (wid + half * 4) * 16;
#pragma unroll
        for (int ot = 0; ot < 2; ++ot) {
            f32x4 acc = (half == 0) ? (ot == 0 ? aA0 : aA1) : (ot == 0 ? aB0 : aB1);
#pragma unroll
            for (int r = 0; r < 4; ++r) {
                int oc = ot * 16 + quad * 4 + r;
                int sl = sl_base + col;
                float val = 0.0f;
                if (oc < INTER && sl < 120) {
                    val = acc[r] + db1[oc];
                    dbuf[(b * INTER + oc) * FULL + shalf * 120 + sl] = val;
                }
                float s1 = val, s2 = val * val;
                s1 += __shfl_xor(s1, 1); s2 += __shfl_xor(s2, 1);
                s1 += __shfl_xor(s1, 2); s2 += __shfl_xor(s2, 2);
                s1 += __shfl_xor(s1, 4); s2 += __shfl_xor(s2, 4);
                s1 += __shfl_xor(s1, 8); s2 += __shfl_xor(s2, 8);
                if (col == 0 && oc < INTER) {
                    atomicAdd(&sS[oc], s1);
                    atomicAdd(&sS2[oc], s2);
                }
            }
        }
    }
    __syncthreads();
    if (tid < INTER) {
        atomicAdd(&bns[tid], sS[tid]);
        atomicAdd(&bns[24 + tid], sS2[tid]);
    }
}

// ---------------------------------------------------------------------------
// k_dec2: decoder conv2 via MFMA with fused BN+tanh staging. (round 15)
// ---------------------------------------------------------------------------
__global__ __launch_bounds__(256) void k_dec2(
    const float* __restrict__ dbuf, const float* __restrict__ bns,
    const float* __restrict__ gma, const float* __restrict__ bta,
    const short* __restrict__ w2D, const float* __restrict__ db2,
    float* __restrict__ oY, float* __restrict__ oYp)
{
    const int blk = blockIdx.x;            // (b*2 + shalf)*5 + octile
    const int octile = blk % 5;
    const int bh = blk / 5;
    const int shalf = bh & 1, b = bh >> 1;
    const int tid = threadIdx.x;
    const int lane = tid & 63, wid = tid >> 6;
    __shared__ __align__(16) short dT[248 * 40];     // 19840 B
    __shared__ float scl[INTER], sft[INTER];

    if (tid < INTER) {
        float m  = bns[tid] * (1.0f / 3840.0f);
        float v  = bns[24 + tid] * (1.0f / 3840.0f) - m * m;
        float rs = rsqrtf(fmaxf(v, 0.0f) + 1e-5f);
        float g  = gma[tid];
        scl[tid] = rs * g;
        sft[tid] = bta[tid] - m * rs * g;
    }
    for (int idx = tid; idx < 1240; idx += 256) ((uint4*)dT)[idx] = make_uint4(0,0,0,0);
    __syncthreads();
    const int qbase = shalf * 120 - 60;
    for (int idx = tid; idx < 248 * 24; idx += 256) {
        int c = idx / 248, pos = idx - c * 248;
        int qy = qbase + pos;
        if (qy >= 0 && qy < FULL) {
            float v = tanhf(dbuf[(b * INTER + c) * FULL + qy] * scl[c] + sft[c]);
            dT[pos * 40 + c] = (short)f2bf(v);
        }
    }
    __syncthreads();

    const int col = lane & 15, quad = lane >> 4;
    f32x4 acc0 = {0,0,0,0}, acc1 = {0,0,0,0};
    const short* bb0 = dT + (wid * 16 + col) * 40 + quad * 8;
    const short* bb1 = dT + ((wid + 4) * 16 + col) * 40 + quad * 8;
    const short* ab  = w2D + (octile * 64 + lane) * 8;
#pragma unroll 8
    for (int m = 0; m < TLEN; ++m) {
        s16x8 af = *(const s16x8*)(ab + m * 2560);       // 5*512 shorts per tap
        s16x8 b0 = *(const s16x8*)(bb0 + m * 40);
        s16x8 b1 = *(const s16x8*)(bb1 + m * 40);
        acc0 = __builtin_amdgcn_mfma_f32_16x16x32_bf16(af, b0, acc0, 0, 0, 0);
        acc1 = __builtin_amdgcn_mfma_f32_16x16x32_bf16(af, b1, acc1, 0, 0, 0);
    }

#pragma unroll
    for (int r = 0; r < 4; ++r) {
        int oc = octile * 16 + quad * 4 + r;
        if (oc < INCH) {
            float bias = db2[oc];
            {
                int sl = wid * 16 + col;                 // <= 63, always valid
                int sg = shalf * 120 + sl;
                float v = acc0[r] + bias;
                oY[(b * INCH + oc) * FULL + sg] = v;
                if (sg < TLEN) oYp[(b * INCH + oc) * TLEN + sg] = v;
            }
            {
                int sl = (wid + 4) * 16 + col;
                if (sl < 120) {
                    int sg = shalf * 120 + sl;
                    float v = acc1[r] + bias;
                    oY[(b * INCH + oc) * FULL + sg] = v;
                    if (sg < TLEN) oYp[(b * INCH + oc) * TLEN + sg] = v;
                }
            }
        }
    }
}

// ---------------------------------------------------------------------------
extern "C" void kernel_launch(void* const* d_in, const int* in_sizes, int n_in,
                              void* d_out, int out_size, void* d_ws, size_t ws_size,
                              hipStream_t stream)
{
    const float* x   = (const float*)d_in[0];
    const float* w1  = (const float*)d_in[1];
    const float* b1  = (const float*)d_in[2];
    const float* lna = (const float*)d_in[3];
    const float* lnb = (const float*)d_in[4];
    const float* w2  = (const float*)d_in[5];
    const float* b2  = (const float*)d_in[6];
    const float* fcw = (const float*)d_in[7];
    const float* fcb = (const float*)d_in[8];
    const float* dw1 = (const float*)d_in[9];
    const float* db1 = (const float*)d_in[10];
    const float* gma = (const float*)d_in[11];
    const float* bta = (const float*)d_in[12];
    const float* dw2 = (const float*)d_in[13];
    const float* db2 = (const float*)d_in[14];

    // Output layout (flat fp32, reference return order):
    float* out  = (float*)d_out;
    float* oY   = out;                 // [16][72][240]
    float* oLat = out + 276480;        // [16][8][121]
    float* oSig = out + 291968;        // [16][8][121]
    float* oP   = out + 307456;
    float* oF   = out + 307584;
    float* oA   = out + 307712;
    float* oB   = out + 307840;
    float* oYp  = out + 307968;        // [16][72][121]

    // Workspace layout (bytes):
    //   [0, 123904)           w2f bf16 fragments (65536 used: 64 frags)
    //   [123904, 156672)      w3f bf16 DFT fragments
    //   [156672, 900096)      w1fA bf16 A-fragments
    //   [900096, 1576128)     fp32: pP/pF/pA/pB (dbuf overlay), sig, bns
    //   [1576128, ...)        Q [16][24][121][240] fp32 -> h3 overlay
    //                         ([240][128] ushort rows after k_prefix_ln);
    //                         after k_enc2 the region is dead and reused:
    //                         [1576128, +619520)  w2D decoder conv2 frags
    //                         [+619520, ...)      w1D decoder conv1 frags
    short* w2f  = (short*)d_ws;
    short* w3f  = (short*)((char*)d_ws + 123904);
    short* w1fA = (short*)((char*)d_ws + 156672);
    float* fb   = (float*)((char*)d_ws + 900096);
    float* pP   = fb;
    float* pF   = pP + 30720;
    float* pA   = pF + 30720;
    float* pB   = pA + 30720;
    float* dbuf = fb;                  // overlay (temporally disjoint)
    float* sig  = fb + 122880;         // 46080
    float* bns  = sig + 46080;         // 48
    float* Q    = (float*)((char*)d_ws + 1576128);
    short* w2D  = (short*)((char*)d_ws + 1576128);            // Q overlay
    short* w1D  = (short*)((char*)d_ws + 1576128 + 619520);   // Q overlay

    hipMemsetAsync(bns, 0, 48 * sizeof(float), stream);
    k_prep_all<<<1644, 256, 0, stream>>>(w2, w1, w2f, w3f, w1fA);
    k_q<<<512, 256, 0, stream>>>(x, w1fA, Q);
    k_prefix_ln<<<384, 256, 0, stream>>>(Q, b1, lna, lnb);
    k_enc2<<<1920, 256, 0, stream>>>(Q, w2f, w3f, b2, fcw, fcb,
                                     pP, pF, pA, pB, oLat, oP, oF, oA, oB);
    k_prep_dec<<<1334, 256, 0, stream>>>(dw1, dw2, w1D, w2D);
    k_signal<<<384, 256, 0, stream>>>(pP, pF, pA, pB, sig, oSig);
    k_dec1<<<32, 256, 0, stream>>>(sig, w1D, db1, dbuf, bns);
    k_dec2<<<160, 256, 0, stream>>>(dbuf, bns, gma, bta, w2D, db2, oY, oYp);
}

// Round 12
// 258.620 us; speedup vs baseline: 1.1508x; 1.1508x over previous
//
#include <hip/hip_runtime.h>
#include <math.h>

// ---------------------------------------------------------------------------
// PAE pipeline on MI355X. Round 25:
//   k_prefix_ln: REVERTED to the round-21/22 verified form. Round-24's
//           LDS-resident version collapsed occupancy to 8.7% (1 blk/CU,
//           125KB LDS) and ran 103us -- dependent 121-step chains with only
//           4 waves/CU to hide them. Occupancy > traffic for this kernel.
//   k_signal / k_prep_all: sin/cos via v_sin_f32/v_cos_f32 builtins (input
//           already in revolutions; 1 instr vs ~40-instr libm sinf in
//           k_signal's ~90-iter inner loop). HW sin error ~1ulp << bf16.
//   Everything else byte-identical to round 22 (262.7us verified).
// ---------------------------------------------------------------------------

#define INCH   72
#define TLEN   121
#define FULL   240
#define INTER  24
#define EMB    8
#define LP     360
#define NWIN   3840

typedef __attribute__((ext_vector_type(8)))  short s16x8;
typedef __attribute__((ext_vector_type(4)))  float f32x4;

__device__ __forceinline__ unsigned short f2bf(float f) {
    unsigned u = __float_as_uint(f);
    unsigned r = ((u >> 16) & 1u) + 0x7FFFu;
    return (unsigned short)((u + r) >> 16);
}
__device__ __forceinline__ float bf2f(unsigned short u) {
    return __uint_as_float((unsigned)u << 16);
}

// ---------------------------------------------------------------------------
// k_prep_all: w2f | w3f | w1fA in one launch. (round 17: w2f padded to 64)
// ---------------------------------------------------------------------------
__global__ __launch_bounds__(256) void k_prep_all(
    const float* __restrict__ w2, const float* __restrict__ w1,
    short* __restrict__ w2f, short* __restrict__ w3f, short* __restrict__ w1fA)
{
    int gid = blockIdx.x * 256 + threadIdx.x;
    if (gid < 32768) {                                   // w2f (packed pairs, 64 frags)
        int idx = gid;
        int j = idx & 7, ln = (idx >> 3) & 63, s = idx >> 9;   // s 0..63
        int nn = ln & 15, c = (ln >> 4) * 8 + j;
        int e = nn & 7;
        int tap = 2 * s + (nn >> 3);
        float v = (c < INTER && tap <= 120) ? w2[(e * INTER + c) * TLEN + tap] : 0.0f;
        w2f[idx] = (short)f2bf(v);
    } else if (gid < 49152) {                            // w3f
        int idx = gid - 32768;
        int j = idx & 7, ln = (idx >> 3) & 63, tl = (idx >> 9) & 7, ch = idx >> 12;
        int t = (ln >> 4) * 8 + j + ch * 32;
        int colIdx = (tl & 3) * 16 + (ln & 15);
        int k = colIdx + 1;
        float v = 0.0f;
        if (t < TLEN && colIdx < 60) {
            int mm = (k * t) % 121;
            float rev = (float)mm * (1.0f / 121.0f);     // revolutions
            float s = __builtin_amdgcn_sinf(rev);        // v_sin_f32
            float c = __builtin_amdgcn_cosf(rev);        // v_cos_f32
            v = (tl < 4) ? c : -s;
        }
        w3f[idx] = (short)f2bf(v);
    } else if (gid < 420864) {                           // w1fA
        int idx = gid - 49152;
        int j = idx & 7, ln = (idx >> 3) & 63;
        int rest = idx >> 9;
        int ch = rest % 3;
        int rest2 = rest / 3;
        int ot = rest2 & 1, tap = rest2 >> 1;
        int o = ot * 16 + (ln & 15);
        int c = (ln >> 4) * 8 + j + ch * 32;
        float v = (o < INTER && c < INCH) ? w1[(o * INCH + c) * TLEN + tap] : 0.0f;
        w1fA[idx] = (short)f2bf(v);
    }
}

// ---------------------------------------------------------------------------
// k_prep_dec: bf16 MFMA fragments for the decoder convs. (round 15)
// ---------------------------------------------------------------------------
__global__ __launch_bounds__(256) void k_prep_dec(
    const float* __restrict__ dw1, const float* __restrict__ dw2,
    short* __restrict__ w1D, short* __restrict__ w2D)
{
    int gid = blockIdx.x * 256 + threadIdx.x;
    if (gid < 309760) {                                  // w2D
        int j = gid & 7, lane = (gid >> 3) & 63;
        int rest = gid >> 9;                             // m*5 + octile
        int ot = rest % 5, m = rest / 5;
        int oc = ot * 16 + (lane & 15);
        int c  = (lane >> 4) * 8 + j;
        float v = (oc < INCH && c < INTER) ? dw2[(oc * INTER + c) * TLEN + m] : 0.0f;
        w2D[gid] = (short)f2bf(v);
    } else if (gid < 341504) {                           // w1D
        int idx = gid - 309760;
        int j = idx & 7, lane = (idx >> 3) & 63;
        int rest = idx >> 9;                             // st*2 + octile
        int ot = rest & 1, st = rest >> 1;
        int oc = ot * 16 + (lane & 15);
        int m  = st * 4 + (lane >> 4);
        float v = (oc < INTER && m < TLEN) ? dw1[(oc * EMB + j) * TLEN + m] : 0.0f;
        w1D[idx] = (short)f2bf(v);
    }
}

// ---------------------------------------------------------------------------
// k_q: Q[b][o][m][s] = sum_c w1[o,c,m] * x[b,c,(s+m)%240] via MFMA.
// Round 22: swapped operands (A = x rows=s, B = w1 cols=o) -> float4 stores;
// grid 512 (16 m-groups of 8 taps) -> 2 blocks/CU.
// ---------------------------------------------------------------------------
__global__ __launch_bounds__(256) void k_q(
    const float* __restrict__ x, const short* __restrict__ w1fA,
    float* __restrict__ Q)
{
    const int blk = blockIdx.x;
    const int mg2 = blk & 15, sh = (blk >> 4) & 1, b = blk >> 5;
    const int tid = threadIdx.x;
    const int lane = tid & 63, wid = tid >> 6;
    const int s0 = sh * 120;
    __shared__ __align__(16) short xTb[248 * 104];   // 51584 B

    for (int idx = tid; idx < (248 * 104) / 8; idx += 256)
        ((uint4*)xTb)[idx] = make_uint4(0, 0, 0, 0);
    __syncthreads();
    for (int idx = tid; idx < 72 * 248; idx += 256) {
        int c = idx / 248, l = idx - c * 248;
        int g = s0 + l; g -= (g >= FULL) ? FULL : 0;
        xTb[l * 104 + c] = (short)f2bf(x[(b * INCH + c) * FULL + g]);
    }
    __syncthreads();

    const int ntaps = (mg2 < 15) ? 8 : 1;            // taps 120 only in group 15
    const int m16 = lane & 15, quad = lane >> 4;
    for (int j = 0; j < ntaps; ++j) {
        const int m = mg2 * 8 + j;
        s16x8 bw[2][3];                              // w1 B-fragments (cols=o)
#pragma unroll
        for (int ot = 0; ot < 2; ++ot)
#pragma unroll
            for (int ch = 0; ch < 3; ++ch)
                bw[ot][ch] = *(const s16x8*)(w1fA + (((m * 2 + ot) * 3 + ch) * 64 + lane) * 8);
#pragma unroll
        for (int tt = 0; tt < 2; ++tt) {
            const int ts = (wid + tt * 4) * 16;      // s-tile base
            const short* arow = xTb + (ts + m16 + m) * 104 + quad * 8;
            s16x8 a0 = *(const s16x8*)(arow);        // A rows = s, k = c
            s16x8 a1 = *(const s16x8*)(arow + 32);
            s16x8 a2 = *(const s16x8*)(arow + 64);
#pragma unroll
            for (int ot = 0; ot < 2; ++ot) {
                f32x4 acc = {0.0f, 0.0f, 0.0f, 0.0f};
                acc = __builtin_amdgcn_mfma_f32_16x16x32_bf16(a0, bw[ot][0], acc, 0, 0, 0);
                acc = __builtin_amdgcn_mfma_f32_16x16x32_bf16(a1, bw[ot][1], acc, 0, 0, 0);
                acc = __builtin_amdgcn_mfma_f32_16x16x32_bf16(a2, bw[ot][2], acc, 0, 0, 0);
                const int o = ot * 16 + m16;         // C col = o
                if (o < INTER) {
                    const int sbase = ts + quad * 4; // C row = s
                    float* qp = Q + ((size_t)(b * INTER + o) * TLEN + m) * FULL + s0 + sbase;
                    if (sbase + 3 < 120) {
                        *(float4*)qp = make_float4(acc[0], acc[1], acc[2], acc[3]);
                    } else {
#pragma unroll
                        for (int r = 0; r < 4; ++r)
                            if (sbase + r < 120) qp[r] = acc[r];
                    }
                }
            }
        }
    }
}

// ---------------------------------------------------------------------------
// k_prefix_ln: fused prefix + conv1-diff + LN + tanh -> bf16 h3 overlay.
// (round 21/22 verified form: hls stride-121 conflict-free; dump repacks to
// [240][128] zero-padded global rows for k_enc2's staging.)
// ---------------------------------------------------------------------------
__global__ __launch_bounds__(256) void k_prefix_ln(
    float* __restrict__ Q, const float* __restrict__ b1,
    const float* __restrict__ lna, const float* __restrict__ lnb)
{
    const int blk = blockIdx.x;          // b*24 + o
    const int o = blk % INTER;
    const int tid = threadIdx.x;
    __shared__ float r121[FULL];                              // 960 B
    __shared__ __align__(16) unsigned short hls[FULL * TLEN]; // 58080 B
    float* Rg = Q + (size_t)blk * (TLEN * FULL);

    // --- prefix phase: in-place inclusive prefix over taps, col = tid ---
    if (tid < FULL) {
        float* Qc = Rg + tid;
        float P = 0.0f;
        for (int m = 0; m < 120; m += 4) {
            float q0 = Qc[m * FULL];
            float q1 = Qc[(m + 1) * FULL];
            float q2 = Qc[(m + 2) * FULL];
            float q3 = Qc[(m + 3) * FULL];
            P += q0; Qc[m * FULL]       = P;
            P += q1; Qc[(m + 1) * FULL] = P;
            P += q2; Qc[(m + 2) * FULL] = P;
            P += q3; Qc[(m + 3) * FULL] = P;
        }
        P += Qc[120 * FULL];
        Qc[120 * FULL] = P;              // row 120 = R[121]
        r121[tid] = P;                   // register -> LDS, no re-read
    }
    __syncthreads();

    if (tid < FULL) {
        const int n = tid;
        const float bias = b1[o];
        unsigned short* hrow = hls + n * TLEN;
        float s = 0.0f, s2 = 0.0f;
        // pass 1: compute v, cache bf16(v), accumulate stats (fp32 v)
        for (int i = 0; i < 60; ++i) {                   // lo = 60-i >= 1
            int st = n + i - 120; st += (st < 0) ? FULL : 0;
            float v = r121[st] - Rg[(59 - i) * FULL + st] + bias;
            s += v; s2 += v * v;
            hrow[i] = f2bf(v);
        }
        {                                                // i = 60: lo = 0
            int st = n - 60; st += (st < 0) ? FULL : 0;
            float v = r121[st] + bias;
            s += v; s2 += v * v;
            hrow[60] = f2bf(v);
        }
        for (int i = 61; i < TLEN; ++i) {                // up = 181-i, lo = 0
            int st = n + i - 120; st += (st < 0) ? FULL : 0;
            float v = Rg[(180 - i) * FULL + st] + bias;
            s += v; s2 += v * v;
            hrow[i] = f2bf(v);
        }
        float mean = s * (1.0f / 121.0f);
        float var  = fmaxf((s2 - s * mean) * (1.0f / 120.0f), 0.0f);   // ddof=1
        float inv  = 1.0f / (sqrtf(var) + 1e-5f);                      // (std+eps)
        // pass 2: LDS-only transform + tanh
        for (int i = 0; i < TLEN; ++i) {
            float v = bf2f(hrow[i]);
            v = (v - mean) * inv * lna[i] + lnb[i];
            hrow[i] = f2bf(tanhf(v));
        }
    }
    __syncthreads();
    // dump: repack stride-121 LDS rows -> [240][128] global ushort rows
    // (zero-padded cols 121..127). Item = (row, 16B chunk): global stores
    // fully contiguous per wave; LDS reads worst-case free 2-way aliasing.
    {
        unsigned short* dstg = (unsigned short*)Rg;
        for (int idx = tid; idx < 3840; idx += 256) {
            int row = idx >> 4, c = idx & 15;
            const unsigned short* src = hls + row * TLEN + c * 8;
            unsigned v0, v1, v2, v3;
            if (c < 15) {
                v0 = (unsigned)src[0] | ((unsigned)src[1] << 16);
                v1 = (unsigned)src[2] | ((unsigned)src[3] << 16);
                v2 = (unsigned)src[4] | ((unsigned)src[5] << 16);
                v3 = (unsigned)src[6] | ((unsigned)src[7] << 16);
            } else {                     // shorts 120..127: only 120 is real
                v0 = (unsigned)src[0];
                v1 = 0; v2 = 0; v3 = 0;
            }
            uint4 v = make_uint4(v0, v1, v2, v3);
            *(uint4*)(dstg + row * 128 + c * 8) = v;
        }
    }
}

// ---------------------------------------------------------------------------
// enc2 epilogue (verified round-18 code, per window). Caller must have
// synced; overlay buffers live in hTA. Trailing sync included.
// ---------------------------------------------------------------------------
__device__ __forceinline__ void enc2_epilogue(
    f32x4 acc0, f32x4 acc1, int gwin, int nwin, int b,
    int tid, int lane, int wid,
    float* latf, short* latb, float* S0, float* S1, float* vv, float* bm,
    const short* __restrict__ w3f, const float* __restrict__ b2,
    const float* __restrict__ fcw, const float* __restrict__ fcb,
    float* __restrict__ pP, float* __restrict__ pF,
    float* __restrict__ pA, float* __restrict__ pB,
    float* __restrict__ oLat, float* __restrict__ oP, float* __restrict__ oF,
    float* __restrict__ oA, float* __restrict__ oB)
{
    const int m16 = lane & 15, quad = lane >> 4;
    const int t0 = wid * 32;

    // E pass (cols 0..7): plain stores cover latf[e][0..127]
    if (m16 < 8) {
#pragma unroll
        for (int r = 0; r < 4; ++r) {
            latf[m16 * 132 + t0 +      quad * 4 + r] = acc0[r];
            latf[m16 * 132 + t0 + 16 + quad * 4 + r] = acc1[r];
        }
    }
    if (tid < 8) { S0[tid] = 0.0f; S1[tid] = 0.0f; }
    if (tid < 64) {                                  // latb pad cols 121..127 = 0
        int e_ = tid >> 3, i = 121 + (tid & 7);
        if (i < 128) latb[e_ * 136 + i] = 0;
    }
    __syncthreads();
    // O pass (cols 8..15): accumulate at i-1 (distinct (e,i) per lane)
    if (m16 >= 8) {
        const int e_ = m16 - 8;
#pragma unroll
        for (int r = 0; r < 4; ++r) {
            int i0 = t0 + quad * 4 + r - 1;
            if (i0 >= 0) latf[e_ * 132 + i0] += acc0[r];
            latf[e_ * 132 + t0 + 15 + quad * 4 + r] += acc1[r];
        }
    }
    __syncthreads();
    // bias + bf16 mirror
    for (int idx = tid; idx < EMB * TLEN; idx += 256) {
        int e_ = idx / TLEN, i = idx - e_ * TLEN;
        float v = latf[e_ * 132 + i] + b2[e_];
        latf[e_ * 132 + i] = v;
        latb[e_ * 136 + i] = (short)f2bf(v);
    }
    __syncthreads();

    // --- DFT via MFMA (lanes e>=8 feed zero A rows) ---
    {
        f32x4 accR = {0,0,0,0};
        f32x4 accI = {0,0,0,0};
#pragma unroll
        for (int ch = 0; ch < 4; ++ch) {
            s16x8 afr = {0,0,0,0,0,0,0,0};
            if (m16 < 8) afr = *(const s16x8*)(latb + m16 * 136 + quad * 8 + ch * 32);
            s16x8 br = *(const s16x8*)(w3f + (((ch * 8) + wid) * 64 + lane) * 8);
            s16x8 bi = *(const s16x8*)(w3f + (((ch * 8) + 4 + wid) * 64 + lane) * 8);
            accR = __builtin_amdgcn_mfma_f32_16x16x32_bf16(afr, br, accR, 0, 0, 0);
            accI = __builtin_amdgcn_mfma_f32_16x16x32_bf16(afr, bi, accI, 0, 0, 0);
        }
        const int colj = m16;
        const int col  = wid * 16 + colj;
        const float fw = 0.5f * (float)(col + 1);
#pragma unroll
        for (int r = 0; r < 4; ++r) {
            float pw = (col < 60) ? (accR[r] * accR[r] + accI[r] * accI[r]) : 0.0f;
            float s1 = pw * fw;
#pragma unroll
            for (int off = 1; off < 16; off <<= 1) {
                pw += __shfl_xor(pw, off);
                s1 += __shfl_xor(s1, off);
            }
            if (colj == 0) {
                int e = quad * 4 + r;
                if (e < EMB) { atomicAdd(&S0[e], pw); atomicAdd(&S1[e], s1); }
            }
        }
    }
    // --- fc (threads 0..127) + channel means (128..191), 8-lane reductions ---
    if (tid < 128) {
        const int outi = tid >> 3, l8 = tid & 7;
        const int e_ = outi >> 1;
        const float* fr = fcw + outi * TLEN;
        float av = 0.0f;
        for (int t = l8; t < TLEN; t += 8) av += latf[e_ * 132 + t] * fr[t];
        av += __shfl_xor(av, 1); av += __shfl_xor(av, 2); av += __shfl_xor(av, 4);
        if (l8 == 0) vv[outi] = fcb[outi] + av;
    } else if (tid < 192) {
        const int idx2 = tid - 128;
        const int e_ = idx2 >> 3, l8 = idx2 & 7;
        float ssum = 0.0f;
        for (int t = l8; t < TLEN; t += 8) ssum += latf[e_ * 132 + t];
        ssum += __shfl_xor(ssum, 1); ssum += __shfl_xor(ssum, 2); ssum += __shfl_xor(ssum, 4);
        if (l8 == 0) bm[e_] = ssum * (1.0f / 121.0f);
    }
    __syncthreads();

    if (tid < 8) {
        int e_ = tid;
        float fv = S1[e_] / S0[e_];
        float av = 2.0f * sqrtf(S0[e_]) * (1.0f / 121.0f);
        float pv = atan2f(vv[2 * e_ + 1], vv[2 * e_]) * 0.15915494309189535f;
        float bv = bm[e_];
        int gi = gwin * 8 + e_;
        pP[gi] = pv; pF[gi] = fv; pA[gi] = av; pB[gi] = bv;
        if (nwin == 0) {
            oP[b * 8 + e_] = pv;
            oF[b * 8 + e_] = fv;
            oA[b * 8 + e_] = av;
            oB[b * 8 + e_] = bv;
        }
    }
    if (nwin == 0) {
        for (int idx = tid; idx < EMB * TLEN; idx += 256) {
            int e_ = idx / TLEN, i = idx - e_ * TLEN;
            oLat[(b * EMB + e_) * TLEN + i] = latf[e_ * 132 + i];
        }
    }
    __syncthreads();    // next window's epilogue reuses the overlay buffers
}

// ---------------------------------------------------------------------------
// k_enc2: 2-window conv2 MFMA (shared w2f B-fragments) + per-window epilogue.
// Block = (b, nb) -> windows {2nb, 2nb+1}. Grid 1920. (round 20)
// ---------------------------------------------------------------------------
__global__ __launch_bounds__(256, 4) void k_enc2(
    const float* __restrict__ Q, const short* __restrict__ w2f,
    const short* __restrict__ w3f, const float* __restrict__ b2,
    const float* __restrict__ fcw, const float* __restrict__ fcb,
    float* __restrict__ pP, float* __restrict__ pF, float* __restrict__ pA, float* __restrict__ pB,
    float* __restrict__ oLat, float* __restrict__ oP, float* __restrict__ oF,
    float* __restrict__ oA, float* __restrict__ oB)
{
    const int blk = blockIdx.x;          // b*120 + nb
    const int b   = blk / 120, nb = blk - b * 120;
    const int nA  = 2 * nb, nB = 2 * nb + 1;
    const int tid = threadIdx.x;
    const int lane = tid & 63, wid = tid >> 6;

    __shared__ __align__(16) short hTA[248 * 40];    // 19840 B
    __shared__ __align__(16) short hTB[248 * 40];    // 19840 B
    // epilogue overlay on hTA (dead after conv loop):
    float* latf = (float*)hTA;                       // [EMB*132]  4224 B
    short* latb = (short*)((char*)hTA + 4224);       // [EMB*136]  2176 B
    float* S0   = (float*)((char*)hTA + 6400);       // [8]
    float* S1   = (float*)((char*)hTA + 6432);       // [8]
    float* vv   = (float*)((char*)hTA + 6464);       // [16]
    float* bm   = (float*)((char*)hTA + 6528);       // [8]

    for (int idx = tid; idx < 1240; idx += 256) {
        ((uint4*)hTA)[idx] = make_uint4(0,0,0,0);
        ((uint4*)hTB)[idx] = make_uint4(0,0,0,0);
    }
    __syncthreads();

    // staging: coalesced uint4 loads of 128-short-aligned h3 rows, transposed
    // scatter into hT[(60+i)][o]. 768 = 2 windows x 24 ch x 16 uint4.
    for (int idx = tid; idx < 768; idx += 256) {
        int win = (idx >= 384);
        int rem = idx - win * 384;
        int o = rem >> 4, u4 = rem & 15;
        const unsigned short* h3 =
            (const unsigned short*)(Q + (size_t)(b * INTER + o) * (TLEN * FULL));
        uint4 v = *(const uint4*)(h3 + (win ? nB : nA) * 128 + u4 * 8);
        short* hX = win ? hTB : hTA;
        int rbase = (60 + u4 * 8) * 40 + o;
        hX[rbase +   0] = (short)(v.x & 0xFFFF);
        hX[rbase +  40] = (short)(v.x >> 16);
        hX[rbase +  80] = (short)(v.y & 0xFFFF);
        hX[rbase + 120] = (short)(v.y >> 16);
        hX[rbase + 160] = (short)(v.z & 0xFFFF);
        hX[rbase + 200] = (short)(v.z >> 16);
        hX[rbase + 240] = (short)(v.w & 0xFFFF);
        hX[rbase + 280] = (short)(v.w >> 16);
    }
    __syncthreads();

    const int m16 = lane & 15, quad = lane >> 4;
    const int t0 = wid * 32;

    // --- conv2 MFMA: packed tap pairs, 61 steps, 2 windows share bw ---
    f32x4 accA0 = {0,0,0,0}, accA1 = {0,0,0,0};
    f32x4 accB0 = {0,0,0,0}, accB1 = {0,0,0,0};
    const short* aptrA = hTA + (t0 + m16) * 40 + quad * 8;
    const short* aptrB = hTB + (t0 + m16) * 40 + quad * 8;
    s16x8 ringA[8], ringB[8];
#pragma unroll
    for (int j = 0; j < 8; ++j) {
        ringA[j] = *(const s16x8*)(aptrA + 2 * j * 40);
        ringB[j] = *(const s16x8*)(aptrB + 2 * j * 40);
    }
#pragma unroll
    for (int s = 0; s < 61; ++s) {
        const int k = s & 7;
        s16x8 bw  = *(const s16x8*)(w2f + s * 512 + lane * 8);
        s16x8 nwA = *(const s16x8*)(aptrA + (2 * s + 16) * 40);
        s16x8 nwB = *(const s16x8*)(aptrB + (2 * s + 16) * 40);
        accA0 = __builtin_amdgcn_mfma_f32_16x16x32_bf16(ringA[k], bw, accA0, 0, 0, 0);
        accA1 = __builtin_amdgcn_mfma_f32_16x16x32_bf16(nwA,      bw, accA1, 0, 0, 0);
        accB0 = __builtin_amdgcn_mfma_f32_16x16x32_bf16(ringB[k], bw, accB0, 0, 0, 0);
        accB1 = __builtin_amdgcn_mfma_f32_16x16x32_bf16(nwB,      bw, accB1, 0, 0, 0);
        ringA[k] = nwA;
        ringB[k] = nwB;
    }
    __syncthreads();   // hTA dead from here; overlay live

    enc2_epilogue(accA0, accA1, b * FULL + nA, nA, b, tid, lane, wid,
                  latf, latb, S0, S1, vv, bm, w3f, b2, fcw, fcb,
                  pP, pF, pA, pB, oLat, oP, oF, oA, oB);
    enc2_epilogue(accB0, accB1, b * FULL + nB, nB, b, tid, lane, wid,
                  latf, latb, S0, S1, vv, bm, w3f, b2, fcw, fcb,
                  pP, pF, pA, pB, oLat, oP, oF, oA, oB);
}

// ---------------------------------------------------------------------------
// k_signal: sinusoid resynthesis + overlap-add, gather form. (round 18 +
// round 25: sin via v_sin_f32 -- z already in revolutions after fract)
// ---------------------------------------------------------------------------
__global__ __launch_bounds__(256) void k_signal(
    const float* __restrict__ pP, const float* __restrict__ pF,
    const float* __restrict__ pA, const float* __restrict__ pB,
    float* __restrict__ sig, float* __restrict__ oSig)
{
    const int blk = blockIdx.x;          // (b*8 + e)*3 + uc
    const int uc = blk % 3;
    const int be = blk / 3;
    const int b = be >> 3, e = be & 7;
    const int tid = threadIdx.x;
    __shared__ float sp[FULL], sf[FULL], sa[FULL], sb[FULL];
    for (int nn = tid; nn < FULL; nn += 256) {
        int gi = (b * FULL + nn) * 8 + e;
        sp[nn] = pP[gi]; sf[nn] = pF[gi]; sa[nn] = pA[gi]; sb[nn] = pB[gi];
    }
    __syncthreads();
    if (tid < 240) {
        const int u = uc * 120 + (tid >> 1);
        const int half = tid & 1;
        int nlo = (u - 120 > 0) ? (u - 120) : 0;
        int nhi = (u < 239) ? u : 239;
        int mid = (nlo + nhi + 1) >> 1;
        int lo = half ? mid : nlo;
        int hi = half ? nhi : (mid - 1);
        float s = 0.0f;
        for (int nn = lo; nn <= hi; ++nn) {
            float tt = (float)(u - nn);
            float z = sf[nn] * (tt * (1.0f / 60.0f) - 1.0f) + sp[nn];
            z -= floorf(z);
            s += sa[nn] * __builtin_amdgcn_sinf(z) + sb[nn];   // v_sin_f32 (rev)
        }
        s += __shfl_xor(s, 1);
        if (half == 0) {
            float wgt = (u < TLEN) ? (float)(u + 1) : ((u > 239) ? (float)(LP - u) : 121.0f);
            float val = s / wgt;
            sig[(b * EMB + e) * LP + u] = val;
            if (u < TLEN) oSig[(b * EMB + e) * TLEN + u] = val;
        }
    }
}

// ---------------------------------------------------------------------------
// k_dec1: decoder conv1 via MFMA. Block = (b, shalf) = 32 blocks. (round 15)
// ---------------------------------------------------------------------------
__global__ __launch_bounds__(256) void k_dec1(
    const float* __restrict__ sig, const short* __restrict__ w1D, const float* __restrict__ db1,
    float* __restrict__ dbuf, float* __restrict__ bns)
{
    const int blk = blockIdx.x;            // b*2 + shalf
    const int shalf = blk & 1, b = blk >> 1;
    const int tid = threadIdx.x;
    const int lane = tid & 63, wid = tid >> 6;
    __shared__ __align__(16) short yT[256 * 8];      // 4096 B (rows 248..255 stay 0)
    __shared__ float sS[INTER], sS2[INTER];

    if (tid < 256) ((uint4*)yT)[tid] = make_uint4(0, 0, 0, 0);
    if (tid < INTER) { sS[tid] = 0.0f; sS2[tid] = 0.0f; }
    __syncthreads();
    const int qbase = shalf * 120 - 60;
    for (int idx = tid; idx < 248 * 8; idx += 256) {
        int c = idx / 248, pos = idx - c * 248;
        int qy = qbase + pos;
        if (qy >= 0 && qy < FULL)
            yT[pos * 8 + c] = (short)f2bf(sig[(b * EMB + c) * LP + qy + 60]);
    }
    __syncthreads();

    const int col = lane & 15, quad = lane >> 4;
    f32x4 aA0 = {0,0,0,0}, aA1 = {0,0,0,0};   // stile wid   x octile 0/1
    f32x4 aB0 = {0,0,0,0}, aB1 = {0,0,0,0};   // stile wid+4 x octile 0/1
    const short* bb0 = yT + (wid * 16 + col + quad) * 8;
    const short* bb1 = yT + ((wid + 4) * 16 + col + quad) * 8;
#pragma unroll 4
    for (int st = 0; st < 31; ++st) {
        s16x8 a0 = *(const s16x8*)(w1D + ((st * 2 + 0) * 64 + lane) * 8);
        s16x8 a1 = *(const s16x8*)(w1D + ((st * 2 + 1) * 64 + lane) * 8);
        s16x8 b0 = *(const s16x8*)(bb0 + st * 32);
        s16x8 b1 = *(const s16x8*)(bb1 + st * 32);
        aA0 = __builtin_amdgcn_mfma_f32_16x16x32_bf16(a0, b0, aA0, 0, 0, 0);
        aA1 = __builtin_amdgcn_mfma_f32_16x16x32_bf16(a1, b0, aA1, 0, 0, 0);
        aB0 = __builtin_amdgcn_mfma_f32_16x16x32_bf16(a0, b1, aB0, 0, 0, 0);
        aB1 = __builtin_amdgcn_mfma_f32_16x16x32_bf16(a1, b1, aB1, 0, 0, 0);
    }

    // epilogue: bias + store dbuf + masked stats (col-reduce then LDS atomics)
#pragma unroll
    for (int half = 0; half < 2; ++half) {
        const int sl_base = (wid + half * 4) * 16;
#pragma unroll
        for (int ot = 0; ot < 2; ++ot) {
            f32x4 acc = (half == 0) ? (ot == 0 ? aA0 : aA1) : (ot == 0 ? aB0 : aB1);
#pragma unroll
            for (int r = 0; r < 4; ++r) {
                int oc = ot * 16 + quad * 4 + r;
                int sl = sl_base + col;
                float val = 0.0f;
                if (oc < INTER && sl < 120) {
                    val = acc[r] + db1[oc];
                    dbuf[(b * INTER + oc) * FULL + shalf * 120 + sl] = val;
                }
                float s1 = val, s2 = val * val;
                s1 += __shfl_xor(s1, 1); s2 += __shfl_xor(s2, 1);
                s1 += __shfl_xor(s1, 2); s2 += __shfl_xor(s2, 2);
                s1 += __shfl_xor(s1, 4); s2 += __shfl_xor(s2, 4);
                s1 += __shfl_xor(s1, 8); s2 += __shfl_xor(s2, 8);
                if (col == 0 && oc < INTER) {
                    atomicAdd(&sS[oc], s1);
                    atomicAdd(&sS2[oc], s2);
                }
            }
        }
    }
    __syncthreads();
    if (tid < INTER) {
        atomicAdd(&bns[tid], sS[tid]);
        atomicAdd(&bns[24 + tid], sS2[tid]);
    }
}

// ---------------------------------------------------------------------------
// k_dec2: decoder conv2 via MFMA with fused BN+tanh staging. (round 15)
// ---------------------------------------------------------------------------
__global__ __launch_bounds__(256) void k_dec2(
    const float* __restrict__ dbuf, const float* __restrict__ bns,
    const float* __restrict__ gma, const float* __restrict__ bta,
    const short* __restrict__ w2D, const float* __restrict__ db2,
    float* __restrict__ oY, float* __restrict__ oYp)
{
    const int blk = blockIdx.x;            // (b*2 + shalf)*5 + octile
    const int octile = blk % 5;
    const int bh = blk / 5;
    const int shalf = bh & 1, b = bh >> 1;
    const int tid = threadIdx.x;
    const int lane = tid & 63, wid = tid >> 6;
    __shared__ __align__(16) short dT[248 * 40];     // 19840 B
    __shared__ float scl[INTER], sft[INTER];

    if (tid < INTER) {
        float m  = bns[tid] * (1.0f / 3840.0f);
        float v  = bns[24 + tid] * (1.0f / 3840.0f) - m * m;
        float rs = rsqrtf(fmaxf(v, 0.0f) + 1e-5f);
        float g  = gma[tid];
        scl[tid] = rs * g;
        sft[tid] = bta[tid] - m * rs * g;
    }
    for (int idx = tid; idx < 1240; idx += 256) ((uint4*)dT)[idx] = make_uint4(0,0,0,0);
    __syncthreads();
    const int qbase = shalf * 120 - 60;
    for (int idx = tid; idx < 248 * 24; idx += 256) {
        int c = idx / 248, pos = idx - c * 248;
        int qy = qbase + pos;
        if (qy >= 0 && qy < FULL) {
            float v = tanhf(dbuf[(b * INTER + c) * FULL + qy] * scl[c] + sft[c]);
            dT[pos * 40 + c] = (short)f2bf(v);
        }
    }
    __syncthreads();

    const int col = lane & 15, quad = lane >> 4;
    f32x4 acc0 = {0,0,0,0}, acc1 = {0,0,0,0};
    const short* bb0 = dT + (wid * 16 + col) * 40 + quad * 8;
    const short* bb1 = dT + ((wid + 4) * 16 + col) * 40 + quad * 8;
    const short* ab  = w2D + (octile * 64 + lane) * 8;
#pragma unroll 8
    for (int m = 0; m < TLEN; ++m) {
        s16x8 af = *(const s16x8*)(ab + m * 2560);       // 5*512 shorts per tap
        s16x8 b0 = *(const s16x8*)(bb0 + m * 40);
        s16x8 b1 = *(const s16x8*)(bb1 + m * 40);
        acc0 = __builtin_amdgcn_mfma_f32_16x16x32_bf16(af, b0, acc0, 0, 0, 0);
        acc1 = __builtin_amdgcn_mfma_f32_16x16x32_bf16(af, b1, acc1, 0, 0, 0);
    }

#pragma unroll
    for (int r = 0; r < 4; ++r) {
        int oc = octile * 16 + quad * 4 + r;
        if (oc < INCH) {
            float bias = db2[oc];
            {
                int sl = wid * 16 + col;                 // <= 63, always valid
                int sg = shalf * 120 + sl;
                float v = acc0[r] + bias;
                oY[(b * INCH + oc) * FULL + sg] = v;
                if (sg < TLEN) oYp[(b * INCH + oc) * TLEN + sg] = v;
            }
            {
                int sl = (wid + 4) * 16 + col;
                if (sl < 120) {
                    int sg = shalf * 120 + sl;
                    float v = acc1[r] + bias;
                    oY[(b * INCH + oc) * FULL + sg] = v;
                    if (sg < TLEN) oYp[(b * INCH + oc) * TLEN + sg] = v;
                }
            }
        }
    }
}

// ---------------------------------------------------------------------------
extern "C" void kernel_launch(void* const* d_in, const int* in_sizes, int n_in,
                              void* d_out, int out_size, void* d_ws, size_t ws_size,
                              hipStream_t stream)
{
    const float* x   = (const float*)d_in[0];
    const float* w1  = (const float*)d_in[1];
    const float* b1  = (const float*)d_in[2];
    const float* lna = (const float*)d_in[3];
    const float* lnb = (const float*)d_in[4];
    const float* w2  = (const float*)d_in[5];
    const float* b2  = (const float*)d_in[6];
    const float* fcw = (const float*)d_in[7];
    const float* fcb = (const float*)d_in[8];
    const float* dw1 = (const float*)d_in[9];
    const float* db1 = (const float*)d_in[10];
    const float* gma = (const float*)d_in[11];
    const float* bta = (const float*)d_in[12];
    const float* dw2 = (const float*)d_in[13];
    const float* db2 = (const float*)d_in[14];

    // Output layout (flat fp32, reference return order):
    float* out  = (float*)d_out;
    float* oY   = out;                 // [16][72][240]
    float* oLat = out + 276480;        // [16][8][121]
    float* oSig = out + 291968;        // [16][8][121]
    float* oP   = out + 307456;
    float* oF   = out + 307584;
    float* oA   = out + 307712;
    float* oB   = out + 307840;
    float* oYp  = out + 307968;        // [16][72][121]

    // Workspace layout (bytes):
    //   [0, 123904)           w2f bf16 fragments (65536 used: 64 frags)
    //   [123904, 156672)      w3f bf16 DFT fragments
    //   [156672, 900096)      w1fA bf16 A-fragments
    //   [900096, 1576128)     fp32: pP/pF/pA/pB (dbuf overlay), sig, bns
    //   [1576128, ...)        Q [16][24][121][240] fp32 -> h3 overlay
    //                         ([240][128] ushort rows after k_prefix_ln);
    //                         after k_enc2 the region is dead and reused:
    //                         [1576128, +619520)  w2D decoder conv2 frags
    //                         [+619520, ...)      w1D decoder conv1 frags
    short* w2f  = (short*)d_ws;
    short* w3f  = (short*)((char*)d_ws + 123904);
    short* w1fA = (short*)((char*)d_ws + 156672);
    float* fb   = (float*)((char*)d_ws + 900096);
    float* pP   = fb;
    float* pF   = pP + 30720;
    float* pA   = pF + 30720;
    float* pB   = pA + 30720;
    float* dbuf = fb;                  // overlay (temporally disjoint)
    float* sig  = fb + 122880;         // 46080
    float* bns  = sig + 46080;         // 48
    float* Q    = (float*)((char*)d_ws + 1576128);
    short* w2D  = (short*)((char*)d_ws + 1576128);            // Q overlay
    short* w1D  = (short*)((char*)d_ws + 1576128 + 619520);   // Q overlay

    hipMemsetAsync(bns, 0, 48 * sizeof(float), stream);
    k_prep_all<<<1644, 256, 0, stream>>>(w2, w1, w2f, w3f, w1fA);
    k_q<<<512, 256, 0, stream>>>(x, w1fA, Q);
    k_prefix_ln<<<384, 256, 0, stream>>>(Q, b1, lna, lnb);
    k_enc2<<<1920, 256, 0, stream>>>(Q, w2f, w3f, b2, fcw, fcb,
                                     pP, pF, pA, pB, oLat, oP, oF, oA, oB);
    k_prep_dec<<<1334, 256, 0, stream>>>(dw1, dw2, w1D, w2D);
    k_signal<<<384, 256, 0, stream>>>(pP, pF, pA, pB, sig, oSig);
    k_dec1<<<32, 256, 0, stream>>>(sig, w1D, db1, dbuf, bns);
    k_dec2<<<160, 256, 0, stream>>>(dbuf, bns, gma, bta, w2D, db2, oY, oYp);
}

// Round 13
// 251.284 us; speedup vs baseline: 1.1844x; 1.0292x over previous
//
#include <hip/hip_runtime.h>
#include <math.h>

// ---------------------------------------------------------------------------
// PAE pipeline on MI355X. Round 26:
//   k_enc2: the two per-window epilogues fused into ONE (windows A/B have
//           disjoint overlay buffers hTA/hTB): 14 barriers -> 4, tail phases
//           (DFT/fc/bm, 128-192 active threads) do both windows per phase.
//           Per-window arithmetic order unchanged (bit-identical).
//   k_sig_prep: k_signal (blocks 0..383) + k_prep_dec (384..1717) fused into
//           one dispatch (independent work, both post-enc2).
//   k_prep_all: bns zeroing folded in (first 48 threads) -> memset dropped.
//   9 -> 7 dispatches. Everything else identical to round 25 (258.6us).
// ---------------------------------------------------------------------------

#define INCH   72
#define TLEN   121
#define FULL   240
#define INTER  24
#define EMB    8
#define LP     360
#define NWIN   3840

typedef __attribute__((ext_vector_type(8)))  short s16x8;
typedef __attribute__((ext_vector_type(4)))  float f32x4;

__device__ __forceinline__ unsigned short f2bf(float f) {
    unsigned u = __float_as_uint(f);
    unsigned r = ((u >> 16) & 1u) + 0x7FFFu;
    return (unsigned short)((u + r) >> 16);
}
__device__ __forceinline__ float bf2f(unsigned short u) {
    return __uint_as_float((unsigned)u << 16);
}

// ---------------------------------------------------------------------------
// k_prep_all: w2f | w3f | w1fA in one launch + bns zero (round 26).
// ---------------------------------------------------------------------------
__global__ __launch_bounds__(256) void k_prep_all(
    const float* __restrict__ w2, const float* __restrict__ w1,
    short* __restrict__ w2f, short* __restrict__ w3f, short* __restrict__ w1fA,
    float* __restrict__ bns)
{
    int gid = blockIdx.x * 256 + threadIdx.x;
    if (gid < 48) bns[gid] = 0.0f;                       // replaces memset
    if (gid < 32768) {                                   // w2f (packed pairs, 64 frags)
        int idx = gid;
        int j = idx & 7, ln = (idx >> 3) & 63, s = idx >> 9;   // s 0..63
        int nn = ln & 15, c = (ln >> 4) * 8 + j;
        int e = nn & 7;
        int tap = 2 * s + (nn >> 3);
        float v = (c < INTER && tap <= 120) ? w2[(e * INTER + c) * TLEN + tap] : 0.0f;
        w2f[idx] = (short)f2bf(v);
    } else if (gid < 49152) {                            // w3f
        int idx = gid - 32768;
        int j = idx & 7, ln = (idx >> 3) & 63, tl = (idx >> 9) & 7, ch = idx >> 12;
        int t = (ln >> 4) * 8 + j + ch * 32;
        int colIdx = (tl & 3) * 16 + (ln & 15);
        int k = colIdx + 1;
        float v = 0.0f;
        if (t < TLEN && colIdx < 60) {
            int mm = (k * t) % 121;
            float rev = (float)mm * (1.0f / 121.0f);     // revolutions
            float s = __builtin_amdgcn_sinf(rev);        // v_sin_f32
            float c = __builtin_amdgcn_cosf(rev);        // v_cos_f32
            v = (tl < 4) ? c : -s;
        }
        w3f[idx] = (short)f2bf(v);
    } else if (gid < 420864) {                           // w1fA
        int idx = gid - 49152;
        int j = idx & 7, ln = (idx >> 3) & 63;
        int rest = idx >> 9;
        int ch = rest % 3;
        int rest2 = rest / 3;
        int ot = rest2 & 1, tap = rest2 >> 1;
        int o = ot * 16 + (ln & 15);
        int c = (ln >> 4) * 8 + j + ch * 32;
        float v = (o < INTER && c < INCH) ? w1[(o * INCH + c) * TLEN + tap] : 0.0f;
        w1fA[idx] = (short)f2bf(v);
    }
}

// ---------------------------------------------------------------------------
// k_q: Q[b][o][m][s] = sum_c w1[o,c,m] * x[b,c,(s+m)%240] via MFMA.
// (round 22 verified: A = x rows=s, B = w1 cols=o -> float4 stores; grid 512)
// ---------------------------------------------------------------------------
__global__ __launch_bounds__(256) void k_q(
    const float* __restrict__ x, const short* __restrict__ w1fA,
    float* __restrict__ Q)
{
    const int blk = blockIdx.x;
    const int mg2 = blk & 15, sh = (blk >> 4) & 1, b = blk >> 5;
    const int tid = threadIdx.x;
    const int lane = tid & 63, wid = tid >> 6;
    const int s0 = sh * 120;
    __shared__ __align__(16) short xTb[248 * 104];   // 51584 B

    for (int idx = tid; idx < (248 * 104) / 8; idx += 256)
        ((uint4*)xTb)[idx] = make_uint4(0, 0, 0, 0);
    __syncthreads();
    for (int idx = tid; idx < 72 * 248; idx += 256) {
        int c = idx / 248, l = idx - c * 248;
        int g = s0 + l; g -= (g >= FULL) ? FULL : 0;
        xTb[l * 104 + c] = (short)f2bf(x[(b * INCH + c) * FULL + g]);
    }
    __syncthreads();

    const int ntaps = (mg2 < 15) ? 8 : 1;            // taps 120 only in group 15
    const int m16 = lane & 15, quad = lane >> 4;
    for (int j = 0; j < ntaps; ++j) {
        const int m = mg2 * 8 + j;
        s16x8 bw[2][3];                              // w1 B-fragments (cols=o)
#pragma unroll
        for (int ot = 0; ot < 2; ++ot)
#pragma unroll
            for (int ch = 0; ch < 3; ++ch)
                bw[ot][ch] = *(const s16x8*)(w1fA + (((m * 2 + ot) * 3 + ch) * 64 + lane) * 8);
#pragma unroll
        for (int tt = 0; tt < 2; ++tt) {
            const int ts = (wid + tt * 4) * 16;      // s-tile base
            const short* arow = xTb + (ts + m16 + m) * 104 + quad * 8;
            s16x8 a0 = *(const s16x8*)(arow);        // A rows = s, k = c
            s16x8 a1 = *(const s16x8*)(arow + 32);
            s16x8 a2 = *(const s16x8*)(arow + 64);
#pragma unroll
            for (int ot = 0; ot < 2; ++ot) {
                f32x4 acc = {0.0f, 0.0f, 0.0f, 0.0f};
                acc = __builtin_amdgcn_mfma_f32_16x16x32_bf16(a0, bw[ot][0], acc, 0, 0, 0);
                acc = __builtin_amdgcn_mfma_f32_16x16x32_bf16(a1, bw[ot][1], acc, 0, 0, 0);
                acc = __builtin_amdgcn_mfma_f32_16x16x32_bf16(a2, bw[ot][2], acc, 0, 0, 0);
                const int o = ot * 16 + m16;         // C col = o
                if (o < INTER) {
                    const int sbase = ts + quad * 4; // C row = s
                    float* qp = Q + ((size_t)(b * INTER + o) * TLEN + m) * FULL + s0 + sbase;
                    if (sbase + 3 < 120) {
                        *(float4*)qp = make_float4(acc[0], acc[1], acc[2], acc[3]);
                    } else {
#pragma unroll
                        for (int r = 0; r < 4; ++r)
                            if (sbase + r < 120) qp[r] = acc[r];
                    }
                }
            }
        }
    }
}

// ---------------------------------------------------------------------------
// k_prefix_ln: fused prefix + conv1-diff + LN + tanh -> bf16 h3 overlay.
// (round 21/22 verified form)
// ---------------------------------------------------------------------------
__global__ __launch_bounds__(256) void k_prefix_ln(
    float* __restrict__ Q, const float* __restrict__ b1,
    const float* __restrict__ lna, const float* __restrict__ lnb)
{
    const int blk = blockIdx.x;          // b*24 + o
    const int o = blk % INTER;
    const int tid = threadIdx.x;
    __shared__ float r121[FULL];                              // 960 B
    __shared__ __align__(16) unsigned short hls[FULL * TLEN]; // 58080 B
    float* Rg = Q + (size_t)blk * (TLEN * FULL);

    // --- prefix phase: in-place inclusive prefix over taps, col = tid ---
    if (tid < FULL) {
        float* Qc = Rg + tid;
        float P = 0.0f;
        for (int m = 0; m < 120; m += 4) {
            float q0 = Qc[m * FULL];
            float q1 = Qc[(m + 1) * FULL];
            float q2 = Qc[(m + 2) * FULL];
            float q3 = Qc[(m + 3) * FULL];
            P += q0; Qc[m * FULL]       = P;
            P += q1; Qc[(m + 1) * FULL] = P;
            P += q2; Qc[(m + 2) * FULL] = P;
            P += q3; Qc[(m + 3) * FULL] = P;
        }
        P += Qc[120 * FULL];
        Qc[120 * FULL] = P;              // row 120 = R[121]
        r121[tid] = P;                   // register -> LDS, no re-read
    }
    __syncthreads();

    if (tid < FULL) {
        const int n = tid;
        const float bias = b1[o];
        unsigned short* hrow = hls + n * TLEN;
        float s = 0.0f, s2 = 0.0f;
        // pass 1: compute v, cache bf16(v), accumulate stats (fp32 v)
        for (int i = 0; i < 60; ++i) {                   // lo = 60-i >= 1
            int st = n + i - 120; st += (st < 0) ? FULL : 0;
            float v = r121[st] - Rg[(59 - i) * FULL + st] + bias;
            s += v; s2 += v * v;
            hrow[i] = f2bf(v);
        }
        {                                                // i = 60: lo = 0
            int st = n - 60; st += (st < 0) ? FULL : 0;
            float v = r121[st] + bias;
            s += v; s2 += v * v;
            hrow[60] = f2bf(v);
        }
        for (int i = 61; i < TLEN; ++i) {                // up = 181-i, lo = 0
            int st = n + i - 120; st += (st < 0) ? FULL : 0;
            float v = Rg[(180 - i) * FULL + st] + bias;
            s += v; s2 += v * v;
            hrow[i] = f2bf(v);
        }
        float mean = s * (1.0f / 121.0f);
        float var  = fmaxf((s2 - s * mean) * (1.0f / 120.0f), 0.0f);   // ddof=1
        float inv  = 1.0f / (sqrtf(var) + 1e-5f);                      // (std+eps)
        // pass 2: LDS-only transform + tanh
        for (int i = 0; i < TLEN; ++i) {
            float v = bf2f(hrow[i]);
            v = (v - mean) * inv * lna[i] + lnb[i];
            hrow[i] = f2bf(tanhf(v));
        }
    }
    __syncthreads();
    // dump: repack stride-121 LDS rows -> [240][128] global ushort rows
    {
        unsigned short* dstg = (unsigned short*)Rg;
        for (int idx = tid; idx < 3840; idx += 256) {
            int row = idx >> 4, c = idx & 15;
            const unsigned short* src = hls + row * TLEN + c * 8;
            unsigned v0, v1, v2, v3;
            if (c < 15) {
                v0 = (unsigned)src[0] | ((unsigned)src[1] << 16);
                v1 = (unsigned)src[2] | ((unsigned)src[3] << 16);
                v2 = (unsigned)src[4] | ((unsigned)src[5] << 16);
                v3 = (unsigned)src[6] | ((unsigned)src[7] << 16);
            } else {                     // shorts 120..127: only 120 is real
                v0 = (unsigned)src[0];
                v1 = 0; v2 = 0; v3 = 0;
            }
            uint4 v = make_uint4(v0, v1, v2, v3);
            *(uint4*)(dstg + row * 128 + c * 8) = v;
        }
    }
}

// ---------------------------------------------------------------------------
// k_enc2: 2-window conv2 MFMA (shared w2f B-fragments) + FUSED epilogue
// (round 26: one epilogue pass for both windows, 4 barriers total).
// Block = (b, nb) -> windows {2nb, 2nb+1}. Grid 1920.
// ---------------------------------------------------------------------------
__global__ __launch_bounds__(256, 4) void k_enc2(
    const float* __restrict__ Q, const short* __restrict__ w2f,
    const short* __restrict__ w3f, const float* __restrict__ b2,
    const float* __restrict__ fcw, const float* __restrict__ fcb,
    float* __restrict__ pP, float* __restrict__ pF, float* __restrict__ pA, float* __restrict__ pB,
    float* __restrict__ oLat, float* __restrict__ oP, float* __restrict__ oF,
    float* __restrict__ oA, float* __restrict__ oB)
{
    const int blk = blockIdx.x;          // b*120 + nb
    const int b   = blk / 120, nb = blk - b * 120;
    const int nA  = 2 * nb, nB = 2 * nb + 1;
    const int tid = threadIdx.x;
    const int lane = tid & 63, wid = tid >> 6;

    __shared__ __align__(16) short hTA[248 * 40];    // 19840 B
    __shared__ __align__(16) short hTB[248 * 40];    // 19840 B
    // epilogue overlays (hT buffers dead after conv loop):
    float* latfA = (float*)hTA;                      // [EMB*132]  4224 B
    short* latbA = (short*)((char*)hTA + 4224);      // [EMB*136]  2176 B
    float* S0A   = (float*)((char*)hTA + 6400);
    float* S1A   = (float*)((char*)hTA + 6432);
    float* vvA   = (float*)((char*)hTA + 6464);
    float* bmA   = (float*)((char*)hTA + 6528);
    float* latfB = (float*)hTB;
    short* latbB = (short*)((char*)hTB + 4224);
    float* S0B   = (float*)((char*)hTB + 6400);
    float* S1B   = (float*)((char*)hTB + 6432);
    float* vvB   = (float*)((char*)hTB + 6464);
    float* bmB   = (float*)((char*)hTB + 6528);

    for (int idx = tid; idx < 1240; idx += 256) {
        ((uint4*)hTA)[idx] = make_uint4(0,0,0,0);
        ((uint4*)hTB)[idx] = make_uint4(0,0,0,0);
    }
    __syncthreads();

    // staging: coalesced uint4 loads of 128-short h3 rows, transposed scatter
    for (int idx = tid; idx < 768; idx += 256) {
        int win = (idx >= 384);
        int rem = idx - win * 384;
        int o = rem >> 4, u4 = rem & 15;
        const unsigned short* h3 =
            (const unsigned short*)(Q + (size_t)(b * INTER + o) * (TLEN * FULL));
        uint4 v = *(const uint4*)(h3 + (win ? nB : nA) * 128 + u4 * 8);
        short* hX = win ? hTB : hTA;
        int rbase = (60 + u4 * 8) * 40 + o;
        hX[rbase +   0] = (short)(v.x & 0xFFFF);
        hX[rbase +  40] = (short)(v.x >> 16);
        hX[rbase +  80] = (short)(v.y & 0xFFFF);
        hX[rbase + 120] = (short)(v.y >> 16);
        hX[rbase + 160] = (short)(v.z & 0xFFFF);
        hX[rbase + 200] = (short)(v.z >> 16);
        hX[rbase + 240] = (short)(v.w & 0xFFFF);
        hX[rbase + 280] = (short)(v.w >> 16);
    }
    __syncthreads();

    const int m16 = lane & 15, quad = lane >> 4;
    const int t0 = wid * 32;

    // --- conv2 MFMA: packed tap pairs, 61 steps, 2 windows share bw ---
    f32x4 accA0 = {0,0,0,0}, accA1 = {0,0,0,0};
    f32x4 accB0 = {0,0,0,0}, accB1 = {0,0,0,0};
    const short* aptrA = hTA + (t0 + m16) * 40 + quad * 8;
    const short* aptrB = hTB + (t0 + m16) * 40 + quad * 8;
    s16x8 ringA[8], ringB[8];
#pragma unroll
    for (int j = 0; j < 8; ++j) {
        ringA[j] = *(const s16x8*)(aptrA + 2 * j * 40);
        ringB[j] = *(const s16x8*)(aptrB + 2 * j * 40);
    }
#pragma unroll
    for (int s = 0; s < 61; ++s) {
        const int k = s & 7;
        s16x8 bw  = *(const s16x8*)(w2f + s * 512 + lane * 8);
        s16x8 nwA = *(const s16x8*)(aptrA + (2 * s + 16) * 40);
        s16x8 nwB = *(const s16x8*)(aptrB + (2 * s + 16) * 40);
        accA0 = __builtin_amdgcn_mfma_f32_16x16x32_bf16(ringA[k], bw, accA0, 0, 0, 0);
        accA1 = __builtin_amdgcn_mfma_f32_16x16x32_bf16(nwA,      bw, accA1, 0, 0, 0);
        accB0 = __builtin_amdgcn_mfma_f32_16x16x32_bf16(ringB[k], bw, accB0, 0, 0, 0);
        accB1 = __builtin_amdgcn_mfma_f32_16x16x32_bf16(nwB,      bw, accB1, 0, 0, 0);
        ringA[k] = nwA;
        ringB[k] = nwB;
    }
    __syncthreads();   // hT data dead from here; overlays live

    // ---- fused epilogue, phase 1: E-pass stores + S init + latb pad ----
    if (m16 < 8) {
#pragma unroll
        for (int r = 0; r < 4; ++r) {
            latfA[m16 * 132 + t0 +      quad * 4 + r] = accA0[r];
            latfA[m16 * 132 + t0 + 16 + quad * 4 + r] = accA1[r];
            latfB[m16 * 132 + t0 +      quad * 4 + r] = accB0[r];
            latfB[m16 * 132 + t0 + 16 + quad * 4 + r] = accB1[r];
        }
    }
    if (tid < 8) { S0A[tid] = 0.0f; S1A[tid] = 0.0f; S0B[tid] = 0.0f; S1B[tid] = 0.0f; }
    if (tid < 64) {                                  // latb pad cols 121..127 = 0
        int e_ = tid >> 3, i = 121 + (tid & 7);
        if (i < 128) { latbA[e_ * 136 + i] = 0; latbB[e_ * 136 + i] = 0; }
    }
    __syncthreads();
    // ---- phase 2: O-pass (accumulate at i-1; distinct (e,i) per lane) ----
    if (m16 >= 8) {
        const int e_ = m16 - 8;
#pragma unroll
        for (int r = 0; r < 4; ++r) {
            int i0 = t0 + quad * 4 + r - 1;
            if (i0 >= 0) {
                latfA[e_ * 132 + i0] += accA0[r];
                latfB[e_ * 132 + i0] += accB0[r];
            }
            latfA[e_ * 132 + t0 + 15 + quad * 4 + r] += accA1[r];
            latfB[e_ * 132 + t0 + 15 + quad * 4 + r] += accB1[r];
        }
    }
    __syncthreads();
    // ---- phase 3: bias + bf16 mirror ----
    for (int idx = tid; idx < EMB * TLEN; idx += 256) {
        int e_ = idx / TLEN, i = idx - e_ * TLEN;
        float bb = b2[e_];
        float vA = latfA[e_ * 132 + i] + bb;
        float vB = latfB[e_ * 132 + i] + bb;
        latfA[e_ * 132 + i] = vA; latbA[e_ * 136 + i] = (short)f2bf(vA);
        latfB[e_ * 132 + i] = vB; latbB[e_ * 136 + i] = (short)f2bf(vB);
    }
    __syncthreads();
    // ---- phase 4: DFT via MFMA (A then B) + fc + bm ----
    {
        f32x4 aR = {0,0,0,0}, aI = {0,0,0,0};
        f32x4 bR = {0,0,0,0}, bI = {0,0,0,0};
#pragma unroll
        for (int ch = 0; ch < 4; ++ch) {
            s16x8 afrA = {0,0,0,0,0,0,0,0};
            s16x8 afrB = {0,0,0,0,0,0,0,0};
            if (m16 < 8) {
                afrA = *(const s16x8*)(latbA + m16 * 136 + quad * 8 + ch * 32);
                afrB = *(const s16x8*)(latbB + m16 * 136 + quad * 8 + ch * 32);
            }
            s16x8 br = *(const s16x8*)(w3f + (((ch * 8) + wid) * 64 + lane) * 8);
            s16x8 bi = *(const s16x8*)(w3f + (((ch * 8) + 4 + wid) * 64 + lane) * 8);
            aR = __builtin_amdgcn_mfma_f32_16x16x32_bf16(afrA, br, aR, 0, 0, 0);
            aI = __builtin_amdgcn_mfma_f32_16x16x32_bf16(afrA, bi, aI, 0, 0, 0);
            bR = __builtin_amdgcn_mfma_f32_16x16x32_bf16(afrB, br, bR, 0, 0, 0);
            bI = __builtin_amdgcn_mfma_f32_16x16x32_bf16(afrB, bi, bI, 0, 0, 0);
        }
        const int colj = m16;
        const int col  = wid * 16 + colj;
        const float fw = 0.5f * (float)(col + 1);
#pragma unroll
        for (int r = 0; r < 4; ++r) {
            float pwA = (col < 60) ? (aR[r] * aR[r] + aI[r] * aI[r]) : 0.0f;
            float s1A = pwA * fw;
            float pwB = (col < 60) ? (bR[r] * bR[r] + bI[r] * bI[r]) : 0.0f;
            float s1B = pwB * fw;
#pragma unroll
            for (int off = 1; off < 16; off <<= 1) {
                pwA += __shfl_xor(pwA, off);
                s1A += __shfl_xor(s1A, off);
                pwB += __shfl_xor(pwB, off);
                s1B += __shfl_xor(s1B, off);
            }
            if (colj == 0) {
                int e = quad * 4 + r;
                if (e < EMB) {
                    atomicAdd(&S0A[e], pwA); atomicAdd(&S1A[e], s1A);
                    atomicAdd(&S0B[e], pwB); atomicAdd(&S1B[e], s1B);
                }
            }
        }
    }
    if (tid < 128) {
        const int outi = tid >> 3, l8 = tid & 7;
        const int e_ = outi >> 1;
        const float* fr = fcw + outi * TLEN;
        float avA = 0.0f, avB = 0.0f;
        for (int t = l8; t < TLEN; t += 8) {
            float w = fr[t];
            avA += latfA[e_ * 132 + t] * w;
            avB += latfB[e_ * 132 + t] * w;
        }
        avA += __shfl_xor(avA, 1); avA += __shfl_xor(avA, 2); avA += __shfl_xor(avA, 4);
        avB += __shfl_xor(avB, 1); avB += __shfl_xor(avB, 2); avB += __shfl_xor(avB, 4);
        if (l8 == 0) { vvA[outi] = fcb[outi] + avA; vvB[outi] = fcb[outi] + avB; }
    } else if (tid < 192) {
        const int idx2 = tid - 128;
        const int e_ = idx2 >> 3, l8 = idx2 & 7;
        float sA = 0.0f, sB = 0.0f;
        for (int t = l8; t < TLEN; t += 8) {
            sA += latfA[e_ * 132 + t];
            sB += latfB[e_ * 132 + t];
        }
        sA += __shfl_xor(sA, 1); sA += __shfl_xor(sA, 2); sA += __shfl_xor(sA, 4);
        sB += __shfl_xor(sB, 1); sB += __shfl_xor(sB, 2); sB += __shfl_xor(sB, 4);
        if (l8 == 0) { bmA[e_] = sA * (1.0f / 121.0f); bmB[e_] = sB * (1.0f / 121.0f); }
    }
    __syncthreads();
    // ---- phase 5: final params + outputs ----
    if (tid < 8) {
        int e_ = tid;
        {
            float fv = S1A[e_] / S0A[e_];
            float av = 2.0f * sqrtf(S0A[e_]) * (1.0f / 121.0f);
            float pv = atan2f(vvA[2 * e_ + 1], vvA[2 * e_]) * 0.15915494309189535f;
            float bv = bmA[e_];
            int gi = (b * FULL + nA) * 8 + e_;
            pP[gi] = pv; pF[gi] = fv; pA[gi] = av; pB[gi] = bv;
            if (nA == 0) {
                oP[b * 8 + e_] = pv; oF[b * 8 + e_] = fv;
                oA[b * 8 + e_] = av; oB[b * 8 + e_] = bv;
            }
        }
        {
            float fv = S1B[e_] / S0B[e_];
            float av = 2.0f * sqrtf(S0B[e_]) * (1.0f / 121.0f);
            float pv = atan2f(vvB[2 * e_ + 1], vvB[2 * e_]) * 0.15915494309189535f;
            float bv = bmB[e_];
            int gi = (b * FULL + nB) * 8 + e_;
            pP[gi] = pv; pF[gi] = fv; pA[gi] = av; pB[gi] = bv;
        }
    }
    if (nA == 0) {
        for (int idx = tid; idx < EMB * TLEN; idx += 256) {
            int e_ = idx / TLEN, i = idx - e_ * TLEN;
            oLat[(b * EMB + e_) * TLEN + i] = latfA[e_ * 132 + i];
        }
    }
}

// ---------------------------------------------------------------------------
// k_sig_prep: fused k_signal (blocks 0..383) + k_prep_dec (blocks 384..1717).
// Independent work, both run right after k_enc2.
// ---------------------------------------------------------------------------
__global__ __launch_bounds__(256) void k_sig_prep(
    const float* __restrict__ pP, const float* __restrict__ pF,
    const float* __restrict__ pA, const float* __restrict__ pB,
    float* __restrict__ sig, float* __restrict__ oSig,
    const float* __restrict__ dw1, const float* __restrict__ dw2,
    short* __restrict__ w1D, short* __restrict__ w2D)
{
    const int tid = threadIdx.x;
    if (blockIdx.x >= 384) {                 // ---- prep_dec part ----
        int gid = (blockIdx.x - 384) * 256 + tid;
        if (gid < 309760) {                                  // w2D
            int j = gid & 7, lane = (gid >> 3) & 63;
            int rest = gid >> 9;                             // m*5 + octile
            int ot = rest % 5, m = rest / 5;
            int oc = ot * 16 + (lane & 15);
            int c  = (lane >> 4) * 8 + j;
            float v = (oc < INCH && c < INTER) ? dw2[(oc * INTER + c) * TLEN + m] : 0.0f;
            w2D[gid] = (short)f2bf(v);
        } else if (gid < 341504) {                           // w1D
            int idx = gid - 309760;
            int j = idx & 7, lane = (idx >> 3) & 63;
            int rest = idx >> 9;                             // st*2 + octile
            int ot = rest & 1, st = rest >> 1;
            int oc = ot * 16 + (lane & 15);
            int m  = st * 4 + (lane >> 4);
            float v = (oc < INTER && m < TLEN) ? dw1[(oc * EMB + j) * TLEN + m] : 0.0f;
            w1D[idx] = (short)f2bf(v);
        }
        return;
    }
    // ---- signal part ----
    const int blk = blockIdx.x;          // (b*8 + e)*3 + uc
    const int uc = blk % 3;
    const int be = blk / 3;
    const int b = be >> 3, e = be & 7;
    __shared__ float sp[FULL], sf[FULL], sa[FULL], sb[FULL];
    for (int nn = tid; nn < FULL; nn += 256) {
        int gi = (b * FULL + nn) * 8 + e;
        sp[nn] = pP[gi]; sf[nn] = pF[gi]; sa[nn] = pA[gi]; sb[nn] = pB[gi];
    }
    __syncthreads();
    if (tid < 240) {
        const int u = uc * 120 + (tid >> 1);
        const int half = tid & 1;
        int nlo = (u - 120 > 0) ? (u - 120) : 0;
        int nhi = (u < 239) ? u : 239;
        int mid = (nlo + nhi + 1) >> 1;
        int lo = half ? mid : nlo;
        int hi = half ? nhi : (mid - 1);
        float s = 0.0f;
        for (int nn = lo; nn <= hi; ++nn) {
            float tt = (float)(u - nn);
            float z = sf[nn] * (tt * (1.0f / 60.0f) - 1.0f) + sp[nn];
            z -= floorf(z);
            s += sa[nn] * __builtin_amdgcn_sinf(z) + sb[nn];   // v_sin_f32 (rev)
        }
        s += __shfl_xor(s, 1);
        if (half == 0) {
            float wgt = (u < TLEN) ? (float)(u + 1) : ((u > 239) ? (float)(LP - u) : 121.0f);
            float val = s / wgt;
            sig[(b * EMB + e) * LP + u] = val;
            if (u < TLEN) oSig[(b * EMB + e) * TLEN + u] = val;
        }
    }
}

// ---------------------------------------------------------------------------
// k_dec1: decoder conv1 via MFMA. Block = (b, shalf) = 32 blocks. (round 15)
// ---------------------------------------------------------------------------
__global__ __launch_bounds__(256) void k_dec1(
    const float* __restrict__ sig, const short* __restrict__ w1D, const float* __restrict__ db1,
    float* __restrict__ dbuf, float* __restrict__ bns)
{
    const int blk = blockIdx.x;            // b*2 + shalf
    const int shalf = blk & 1, b = blk >> 1;
    const int tid = threadIdx.x;
    const int lane = tid & 63, wid = tid >> 6;
    __shared__ __align__(16) short yT[256 * 8];      // 4096 B (rows 248..255 stay 0)
    __shared__ float sS[INTER], sS2[INTER];

    if (tid < 256) ((uint4*)yT)[tid] = make_uint4(0, 0, 0, 0);
    if (tid < INTER) { sS[tid] = 0.0f; sS2[tid] = 0.0f; }
    __syncthreads();
    const int qbase = shalf * 120 - 60;
    for (int idx = tid; idx < 248 * 8; idx += 256) {
        int c = idx / 248, pos = idx - c * 248;
        int qy = qbase + pos;
        if (qy >= 0 && qy < FULL)
            yT[pos * 8 + c] = (short)f2bf(sig[(b * EMB + c) * LP + qy + 60]);
    }
    __syncthreads();

    const int col = lane & 15, quad = lane >> 4;
    f32x4 aA0 = {0,0,0,0}, aA1 = {0,0,0,0};   // stile wid   x octile 0/1
    f32x4 aB0 = {0,0,0,0}, aB1 = {0,0,0,0};   // stile wid+4 x octile 0/1
    const short* bb0 = yT + (wid * 16 + col + quad) * 8;
    const short* bb1 = yT + ((wid + 4) * 16 + col + quad) * 8;
#pragma unroll 4
    for (int st = 0; st < 31; ++st) {
        s16x8 a0 = *(const s16x8*)(w1D + ((st * 2 + 0) * 64 + lane) * 8);
        s16x8 a1 = *(const s16x8*)(w1D + ((st * 2 + 1) * 64 + lane) * 8);
        s16x8 b0 = *(const s16x8*)(bb0 + st * 32);
        s16x8 b1 = *(const s16x8*)(bb1 + st * 32);
        aA0 = __builtin_amdgcn_mfma_f32_16x16x32_bf16(a0, b0, aA0, 0, 0, 0);
        aA1 = __builtin_amdgcn_mfma_f32_16x16x32_bf16(a1, b0, aA1, 0, 0, 0);
        aB0 = __builtin_amdgcn_mfma_f32_16x16x32_bf16(a0, b1, aB0, 0, 0, 0);
        aB1 = __builtin_amdgcn_mfma_f32_16x16x32_bf16(a1, b1, aB1, 0, 0, 0);
    }

    // epilogue: bias + store dbuf + masked stats (col-reduce then LDS atomics)
#pragma unroll
    for (int half = 0; half < 2; ++half) {
        const int sl_base = (wid + half * 4) * 16;
#pragma unroll
        for (int ot = 0; ot < 2; ++ot) {
            f32x4 acc = (half == 0) ? (ot == 0 ? aA0 : aA1) : (ot == 0 ? aB0 : aB1);
#pragma unroll
            for (int r = 0; r < 4; ++r) {
                int oc = ot * 16 + quad * 4 + r;
                int sl = sl_base + col;
                float val = 0.0f;
                if (oc < INTER && sl < 120) {
                    val = acc[r] + db1[oc];
                    dbuf[(b * INTER + oc) * FULL + shalf * 120 + sl] = val;
                }
                float s1 = val, s2 = val * val;
                s1 += __shfl_xor(s1, 1); s2 += __shfl_xor(s2, 1);
                s1 += __shfl_xor(s1, 2); s2 += __shfl_xor(s2, 2);
                s1 += __shfl_xor(s1, 4); s2 += __shfl_xor(s2, 4);
                s1 += __shfl_xor(s1, 8); s2 += __shfl_xor(s2, 8);
                if (col == 0 && oc < INTER) {
                    atomicAdd(&sS[oc], s1);
                    atomicAdd(&sS2[oc], s2);
                }
            }
        }
    }
    __syncthreads();
    if (tid < INTER) {
        atomicAdd(&bns[tid], sS[tid]);
        atomicAdd(&bns[24 + tid], sS2[tid]);
    }
}

// ---------------------------------------------------------------------------
// k_dec2: decoder conv2 via MFMA with fused BN+tanh staging. (round 15)
// ---------------------------------------------------------------------------
__global__ __launch_bounds__(256) void k_dec2(
    const float* __restrict__ dbuf, const float* __restrict__ bns,
    const float* __restrict__ gma, const float* __restrict__ bta,
    const short* __restrict__ w2D, const float* __restrict__ db2,
    float* __restrict__ oY, float* __restrict__ oYp)
{
    const int blk = blockIdx.x;            // (b*2 + shalf)*5 + octile
    const int octile = blk % 5;
    const int bh = blk / 5;
    const int shalf = bh & 1, b = bh >> 1;
    const int tid = threadIdx.x;
    const int lane = tid & 63, wid = tid >> 6;
    __shared__ __align__(16) short dT[248 * 40];     // 19840 B
    __shared__ float scl[INTER], sft[INTER];

    if (tid < INTER) {
        float m  = bns[tid] * (1.0f / 3840.0f);
        float v  = bns[24 + tid] * (1.0f / 3840.0f) - m * m;
        float rs = rsqrtf(fmaxf(v, 0.0f) + 1e-5f);
        float g  = gma[tid];
        scl[tid] = rs * g;
        sft[tid] = bta[tid] - m * rs * g;
    }
    for (int idx = tid; idx < 1240; idx += 256) ((uint4*)dT)[idx] = make_uint4(0,0,0,0);
    __syncthreads();
    const int qbase = shalf * 120 - 60;
    for (int idx = tid; idx < 248 * 24; idx += 256) {
        int c = idx / 248, pos = idx - c * 248;
        int qy = qbase + pos;
        if (qy >= 0 && qy < FULL) {
            float v = tanhf(dbuf[(b * INTER + c) * FULL + qy] * scl[c] + sft[c]);
            dT[pos * 40 + c] = (short)f2bf(v);
        }
    }
    __syncthreads();

    const int col = lane & 15, quad = lane >> 4;
    f32x4 acc0 = {0,0,0,0}, acc1 = {0,0,0,0};
    const short* bb0 = dT + (wid * 16 + col) * 40 + quad * 8;
    const short* bb1 = dT + ((wid + 4) * 16 + col) * 40 + quad * 8;
    const short* ab  = w2D + (octile * 64 + lane) * 8;
#pragma unroll 8
    for (int m = 0; m < TLEN; ++m) {
        s16x8 af = *(const s16x8*)(ab + m * 2560);       // 5*512 shorts per tap
        s16x8 b0 = *(const s16x8*)(bb0 + m * 40);
        s16x8 b1 = *(const s16x8*)(bb1 + m * 40);
        acc0 = __builtin_amdgcn_mfma_f32_16x16x32_bf16(af, b0, acc0, 0, 0, 0);
        acc1 = __builtin_amdgcn_mfma_f32_16x16x32_bf16(af, b1, acc1, 0, 0, 0);
    }

#pragma unroll
    for (int r = 0; r < 4; ++r) {
        int oc = octile * 16 + quad * 4 + r;
        if (oc < INCH) {
            float bias = db2[oc];
            {
                int sl = wid * 16 + col;                 // <= 63, always valid
                int sg = shalf * 120 + sl;
                float v = acc0[r] + bias;
                oY[(b * INCH + oc) * FULL + sg] = v;
                if (sg < TLEN) oYp[(b * INCH + oc) * TLEN + sg] = v;
            }
            {
                int sl = (wid + 4) * 16 + col;
                if (sl < 120) {
                    int sg = shalf * 120 + sl;
                    float v = acc1[r] + bias;
                    oY[(b * INCH + oc) * FULL + sg] = v;
                    if (sg < TLEN) oYp[(b * INCH + oc) * TLEN + sg] = v;
                }
            }
        }
    }
}

// ---------------------------------------------------------------------------
extern "C" void kernel_launch(void* const* d_in, const int* in_sizes, int n_in,
                              void* d_out, int out_size, void* d_ws, size_t ws_size,
                              hipStream_t stream)
{
    const float* x   = (const float*)d_in[0];
    const float* w1  = (const float*)d_in[1];
    const float* b1  = (const float*)d_in[2];
    const float* lna = (const float*)d_in[3];
    const float* lnb = (const float*)d_in[4];
    const float* w2  = (const float*)d_in[5];
    const float* b2  = (const float*)d_in[6];
    const float* fcw = (const float*)d_in[7];
    const float* fcb = (const float*)d_in[8];
    const float* dw1 = (const float*)d_in[9];
    const float* db1 = (const float*)d_in[10];
    const float* gma = (const float*)d_in[11];
    const float* bta = (const float*)d_in[12];
    const float* dw2 = (const float*)d_in[13];
    const float* db2 = (const float*)d_in[14];

    // Output layout (flat fp32, reference return order):
    float* out  = (float*)d_out;
    float* oY   = out;                 // [16][72][240]
    float* oLat = out + 276480;        // [16][8][121]
    float* oSig = out + 291968;        // [16][8][121]
    float* oP   = out + 307456;
    float* oF   = out + 307584;
    float* oA   = out + 307712;
    float* oB   = out + 307840;
    float* oYp  = out + 307968;        // [16][72][121]

    // Workspace layout (bytes): unchanged from round 22/25.
    short* w2f  = (short*)d_ws;
    short* w3f  = (short*)((char*)d_ws + 123904);
    short* w1fA = (short*)((char*)d_ws + 156672);
    float* fb   = (float*)((char*)d_ws + 900096);
    float* pP   = fb;
    float* pF   = pP + 30720;
    float* pA   = pF + 30720;
    float* pB   = pA + 30720;
    float* dbuf = fb;                  // overlay (temporally disjoint)
    float* sig  = fb + 122880;         // 46080
    float* bns  = sig + 46080;         // 48
    float* Q    = (float*)((char*)d_ws + 1576128);
    short* w2D  = (short*)((char*)d_ws + 1576128);            // Q overlay
    short* w1D  = (short*)((char*)d_ws + 1576128 + 619520);   // Q overlay

    k_prep_all<<<1644, 256, 0, stream>>>(w2, w1, w2f, w3f, w1fA, bns);
    k_q<<<512, 256, 0, stream>>>(x, w1fA, Q);
    k_prefix_ln<<<384, 256, 0, stream>>>(Q, b1, lna, lnb);
    k_enc2<<<1920, 256, 0, stream>>>(Q, w2f, w3f, b2, fcw, fcb,
                                     pP, pF, pA, pB, oLat, oP, oF, oA, oB);
    k_sig_prep<<<1718, 256, 0, stream>>>(pP, pF, pA, pB, sig, oSig,
                                         dw1, dw2, w1D, w2D);
    k_dec1<<<32, 256, 0, stream>>>(sig, w1D, db1, dbuf, bns);
    k_dec2<<<160, 256, 0, stream>>>(dbuf, bns, gma, bta, w2D, db2, oY, oYp);
}

// Round 14
// 233.278 us; speedup vs baseline: 1.2758x; 1.0772x over previous
//
#include <hip/hip_runtime.h>
#include <math.h>

// ---------------------------------------------------------------------------
// PAE pipeline on MI355X. Round 27:
//   k_enc2: staging scatter rewritten. Old form wrote scalar ushorts with
//           u4-stride 160 dwords = 0 mod 32 -> ~32-way bank conflicts
//           (SQ_LDS_BANK_CONFLICT 1.078e7 = ~33% of block crit-path). New:
//           item = (channel-pair op, u4); each thread loads 2 uint4 (rows
//           2op,2op+1) and writes 8 PACKED dwords -> lanes span 12 banks,
//           ~5-way worst case. Conv loop / epilogue untouched.
//   fast_tanh (exp2+rcp, ~7 instr vs ~25 libm) in k_prefix_ln pass-2 and
//           k_dec2 staging; error ~1e-6 rel, below the bf16 quantization
//           both outputs immediately undergo.
//   Everything else identical to round 26 (251.3us verified).
// ---------------------------------------------------------------------------

#define INCH   72
#define TLEN   121
#define FULL   240
#define INTER  24
#define EMB    8
#define LP     360
#define NWIN   3840

typedef __attribute__((ext_vector_type(8)))  short s16x8;
typedef __attribute__((ext_vector_type(4)))  float f32x4;

__device__ __forceinline__ unsigned short f2bf(float f) {
    unsigned u = __float_as_uint(f);
    unsigned r = ((u >> 16) & 1u) + 0x7FFFu;
    return (unsigned short)((u + r) >> 16);
}
__device__ __forceinline__ float bf2f(unsigned short u) {
    return __uint_as_float((unsigned)u << 16);
}
__device__ __forceinline__ float fast_tanh(float x) {
    float cx = fminf(fmaxf(x, -15.0f), 15.0f);
    float t  = __builtin_amdgcn_exp2f(cx * 2.8853900817779268f);  // 2*log2(e)
    return (t - 1.0f) * __builtin_amdgcn_rcpf(t + 1.0f);
}

// ---------------------------------------------------------------------------
// k_prep_all: w2f | w3f | w1fA in one launch + bns zero (round 26).
// ---------------------------------------------------------------------------
__global__ __launch_bounds__(256) void k_prep_all(
    const float* __restrict__ w2, const float* __restrict__ w1,
    short* __restrict__ w2f, short* __restrict__ w3f, short* __restrict__ w1fA,
    float* __restrict__ bns)
{
    int gid = blockIdx.x * 256 + threadIdx.x;
    if (gid < 48) bns[gid] = 0.0f;                       // replaces memset
    if (gid < 32768) {                                   // w2f (packed pairs, 64 frags)
        int idx = gid;
        int j = idx & 7, ln = (idx >> 3) & 63, s = idx >> 9;   // s 0..63
        int nn = ln & 15, c = (ln >> 4) * 8 + j;
        int e = nn & 7;
        int tap = 2 * s + (nn >> 3);
        float v = (c < INTER && tap <= 120) ? w2[(e * INTER + c) * TLEN + tap] : 0.0f;
        w2f[idx] = (short)f2bf(v);
    } else if (gid < 49152) {                            // w3f
        int idx = gid - 32768;
        int j = idx & 7, ln = (idx >> 3) & 63, tl = (idx >> 9) & 7, ch = idx >> 12;
        int t = (ln >> 4) * 8 + j + ch * 32;
        int colIdx = (tl & 3) * 16 + (ln & 15);
        int k = colIdx + 1;
        float v = 0.0f;
        if (t < TLEN && colIdx < 60) {
            int mm = (k * t) % 121;
            float rev = (float)mm * (1.0f / 121.0f);     // revolutions
            float s = __builtin_amdgcn_sinf(rev);        // v_sin_f32
            float c = __builtin_amdgcn_cosf(rev);        // v_cos_f32
            v = (tl < 4) ? c : -s;
        }
        w3f[idx] = (short)f2bf(v);
    } else if (gid < 420864) {                           // w1fA
        int idx = gid - 49152;
        int j = idx & 7, ln = (idx >> 3) & 63;
        int rest = idx >> 9;
        int ch = rest % 3;
        int rest2 = rest / 3;
        int ot = rest2 & 1, tap = rest2 >> 1;
        int o = ot * 16 + (ln & 15);
        int c = (ln >> 4) * 8 + j + ch * 32;
        float v = (o < INTER && c < INCH) ? w1[(o * INCH + c) * TLEN + tap] : 0.0f;
        w1fA[idx] = (short)f2bf(v);
    }
}

// ---------------------------------------------------------------------------
// k_q: Q[b][o][m][s] = sum_c w1[o,c,m] * x[b,c,(s+m)%240] via MFMA.
// (round 22 verified: A = x rows=s, B = w1 cols=o -> float4 stores; grid 512)
// ---------------------------------------------------------------------------
__global__ __launch_bounds__(256) void k_q(
    const float* __restrict__ x, const short* __restrict__ w1fA,
    float* __restrict__ Q)
{
    const int blk = blockIdx.x;
    const int mg2 = blk & 15, sh = (blk >> 4) & 1, b = blk >> 5;
    const int tid = threadIdx.x;
    const int lane = tid & 63, wid = tid >> 6;
    const int s0 = sh * 120;
    __shared__ __align__(16) short xTb[248 * 104];   // 51584 B

    for (int idx = tid; idx < (248 * 104) / 8; idx += 256)
        ((uint4*)xTb)[idx] = make_uint4(0, 0, 0, 0);
    __syncthreads();
    for (int idx = tid; idx < 72 * 248; idx += 256) {
        int c = idx / 248, l = idx - c * 248;
        int g = s0 + l; g -= (g >= FULL) ? FULL : 0;
        xTb[l * 104 + c] = (short)f2bf(x[(b * INCH + c) * FULL + g]);
    }
    __syncthreads();

    const int ntaps = (mg2 < 15) ? 8 : 1;            // taps 120 only in group 15
    const int m16 = lane & 15, quad = lane >> 4;
    for (int j = 0; j < ntaps; ++j) {
        const int m = mg2 * 8 + j;
        s16x8 bw[2][3];                              // w1 B-fragments (cols=o)
#pragma unroll
        for (int ot = 0; ot < 2; ++ot)
#pragma unroll
            for (int ch = 0; ch < 3; ++ch)
                bw[ot][ch] = *(const s16x8*)(w1fA + (((m * 2 + ot) * 3 + ch) * 64 + lane) * 8);
#pragma unroll
        for (int tt = 0; tt < 2; ++tt) {
            const int ts = (wid + tt * 4) * 16;      // s-tile base
            const short* arow = xTb + (ts + m16 + m) * 104 + quad * 8;
            s16x8 a0 = *(const s16x8*)(arow);        // A rows = s, k = c
            s16x8 a1 = *(const s16x8*)(arow + 32);
            s16x8 a2 = *(const s16x8*)(arow + 64);
#pragma unroll
            for (int ot = 0; ot < 2; ++ot) {
                f32x4 acc = {0.0f, 0.0f, 0.0f, 0.0f};
                acc = __builtin_amdgcn_mfma_f32_16x16x32_bf16(a0, bw[ot][0], acc, 0, 0, 0);
                acc = __builtin_amdgcn_mfma_f32_16x16x32_bf16(a1, bw[ot][1], acc, 0, 0, 0);
                acc = __builtin_amdgcn_mfma_f32_16x16x32_bf16(a2, bw[ot][2], acc, 0, 0, 0);
                const int o = ot * 16 + m16;         // C col = o
                if (o < INTER) {
                    const int sbase = ts + quad * 4; // C row = s
                    float* qp = Q + ((size_t)(b * INTER + o) * TLEN + m) * FULL + s0 + sbase;
                    if (sbase + 3 < 120) {
                        *(float4*)qp = make_float4(acc[0], acc[1], acc[2], acc[3]);
                    } else {
#pragma unroll
                        for (int r = 0; r < 4; ++r)
                            if (sbase + r < 120) qp[r] = acc[r];
                    }
                }
            }
        }
    }
}

// ---------------------------------------------------------------------------
// k_prefix_ln: fused prefix + conv1-diff + LN + tanh -> bf16 h3 overlay.
// (round 21/22 verified form; round 27: fast_tanh in pass-2)
// ---------------------------------------------------------------------------
__global__ __launch_bounds__(256) void k_prefix_ln(
    float* __restrict__ Q, const float* __restrict__ b1,
    const float* __restrict__ lna, const float* __restrict__ lnb)
{
    const int blk = blockIdx.x;          // b*24 + o
    const int o = blk % INTER;
    const int tid = threadIdx.x;
    __shared__ float r121[FULL];                              // 960 B
    __shared__ __align__(16) unsigned short hls[FULL * TLEN]; // 58080 B
    float* Rg = Q + (size_t)blk * (TLEN * FULL);

    // --- prefix phase: in-place inclusive prefix over taps, col = tid ---
    if (tid < FULL) {
        float* Qc = Rg + tid;
        float P = 0.0f;
        for (int m = 0; m < 120; m += 4) {
            float q0 = Qc[m * FULL];
            float q1 = Qc[(m + 1) * FULL];
            float q2 = Qc[(m + 2) * FULL];
            float q3 = Qc[(m + 3) * FULL];
            P += q0; Qc[m * FULL]       = P;
            P += q1; Qc[(m + 1) * FULL] = P;
            P += q2; Qc[(m + 2) * FULL] = P;
            P += q3; Qc[(m + 3) * FULL] = P;
        }
        P += Qc[120 * FULL];
        Qc[120 * FULL] = P;              // row 120 = R[121]
        r121[tid] = P;                   // register -> LDS, no re-read
    }
    __syncthreads();

    if (tid < FULL) {
        const int n = tid;
        const float bias = b1[o];
        unsigned short* hrow = hls + n * TLEN;
        float s = 0.0f, s2 = 0.0f;
        // pass 1: compute v, cache bf16(v), accumulate stats (fp32 v)
        for (int i = 0; i < 60; ++i) {                   // lo = 60-i >= 1
            int st = n + i - 120; st += (st < 0) ? FULL : 0;
            float v = r121[st] - Rg[(59 - i) * FULL + st] + bias;
            s += v; s2 += v * v;
            hrow[i] = f2bf(v);
        }
        {                                                // i = 60: lo = 0
            int st = n - 60; st += (st < 0) ? FULL : 0;
            float v = r121[st] + bias;
            s += v; s2 += v * v;
            hrow[60] = f2bf(v);
        }
        for (int i = 61; i < TLEN; ++i) {                // up = 181-i, lo = 0
            int st = n + i - 120; st += (st < 0) ? FULL : 0;
            float v = Rg[(180 - i) * FULL + st] + bias;
            s += v; s2 += v * v;
            hrow[i] = f2bf(v);
        }
        float mean = s * (1.0f / 121.0f);
        float var  = fmaxf((s2 - s * mean) * (1.0f / 120.0f), 0.0f);   // ddof=1
        float inv  = 1.0f / (sqrtf(var) + 1e-5f);                      // (std+eps)
        // pass 2: LDS-only transform + tanh
        for (int i = 0; i < TLEN; ++i) {
            float v = bf2f(hrow[i]);
            v = (v - mean) * inv * lna[i] + lnb[i];
            hrow[i] = f2bf(fast_tanh(v));
        }
    }
    __syncthreads();
    // dump: repack stride-121 LDS rows -> [240][128] global ushort rows
    {
        unsigned short* dstg = (unsigned short*)Rg;
        for (int idx = tid; idx < 3840; idx += 256) {
            int row = idx >> 4, c = idx & 15;
            const unsigned short* src = hls + row * TLEN + c * 8;
            unsigned v0, v1, v2, v3;
            if (c < 15) {
                v0 = (unsigned)src[0] | ((unsigned)src[1] << 16);
                v1 = (unsigned)src[2] | ((unsigned)src[3] << 16);
                v2 = (unsigned)src[4] | ((unsigned)src[5] << 16);
                v3 = (unsigned)src[6] | ((unsigned)src[7] << 16);
            } else {                     // shorts 120..127: only 120 is real
                v0 = (unsigned)src[0];
                v1 = 0; v2 = 0; v3 = 0;
            }
            uint4 v = make_uint4(v0, v1, v2, v3);
            *(uint4*)(dstg + row * 128 + c * 8) = v;
        }
    }
}

// ---------------------------------------------------------------------------
// k_enc2: 2-window conv2 MFMA (shared w2f B-fragments) + FUSED epilogue.
// Round 27: staging via channel-pair packed dword writes (conflict ~5-way,
// was ~32-way). Block = (b, nb) -> windows {2nb, 2nb+1}. Grid 1920.
// ---------------------------------------------------------------------------
__global__ __launch_bounds__(256, 4) void k_enc2(
    const float* __restrict__ Q, const short* __restrict__ w2f,
    const short* __restrict__ w3f, const float* __restrict__ b2,
    const float* __restrict__ fcw, const float* __restrict__ fcb,
    float* __restrict__ pP, float* __restrict__ pF, float* __restrict__ pA, float* __restrict__ pB,
    float* __restrict__ oLat, float* __restrict__ oP, float* __restrict__ oF,
    float* __restrict__ oA, float* __restrict__ oB)
{
    const int blk = blockIdx.x;          // b*120 + nb
    const int b   = blk / 120, nb = blk - b * 120;
    const int nA  = 2 * nb, nB = 2 * nb + 1;
    const int tid = threadIdx.x;
    const int lane = tid & 63, wid = tid >> 6;

    __shared__ __align__(16) short hTA[248 * 40];    // 19840 B
    __shared__ __align__(16) short hTB[248 * 40];    // 19840 B
    // epilogue overlays (hT buffers dead after conv loop):
    float* latfA = (float*)hTA;                      // [EMB*132]  4224 B
    short* latbA = (short*)((char*)hTA + 4224);      // [EMB*136]  2176 B
    float* S0A   = (float*)((char*)hTA + 6400);
    float* S1A   = (float*)((char*)hTA + 6432);
    float* vvA   = (float*)((char*)hTA + 6464);
    float* bmA   = (float*)((char*)hTA + 6528);
    float* latfB = (float*)hTB;
    short* latbB = (short*)((char*)hTB + 4224);
    float* S0B   = (float*)((char*)hTB + 6400);
    float* S1B   = (float*)((char*)hTB + 6432);
    float* vvB   = (float*)((char*)hTB + 6464);
    float* bmB   = (float*)((char*)hTB + 6528);

    for (int idx = tid; idx < 1240; idx += 256) {
        ((uint4*)hTA)[idx] = make_uint4(0,0,0,0);
        ((uint4*)hTB)[idx] = make_uint4(0,0,0,0);
    }
    __syncthreads();

    // staging: item = (win, u4, channel-pair op). Each thread loads 2 uint4
    // (channels 2op, 2op+1; 8 consecutive i) and writes 8 packed dwords to
    // hT[(60+u4*8+k)*40 + 2op..2op+1]. Lanes span 12 consecutive banks per
    // u4-group (~5-way worst case; was ~32-way with scalar ushort stores).
    for (int idx = tid; idx < 384; idx += 256) {
        int win = (idx >= 192);
        int rem = idx - win * 192;
        int op = rem % 12, u4 = rem / 12;            // op 0..11, u4 0..15
        int n = win ? nB : nA;
        const unsigned short* h3a =
            (const unsigned short*)(Q + (size_t)(b * INTER + 2 * op) * (TLEN * FULL));
        const unsigned short* h3b =
            (const unsigned short*)(Q + (size_t)(b * INTER + 2 * op + 1) * (TLEN * FULL));
        uint4 va = *(const uint4*)(h3a + n * 128 + u4 * 8);
        uint4 vb = *(const uint4*)(h3b + n * 128 + u4 * 8);
        unsigned* dst = (unsigned*)(win ? hTB : hTA);
        int base = (60 + u4 * 8) * 20 + op;          // dword offset
        dst[base +   0] = (va.x & 0xFFFFu) | (vb.x << 16);
        dst[base +  20] = (va.x >> 16)     | (vb.x & 0xFFFF0000u);
        dst[base +  40] = (va.y & 0xFFFFu) | (vb.y << 16);
        dst[base +  60] = (va.y >> 16)     | (vb.y & 0xFFFF0000u);
        dst[base +  80] = (va.z & 0xFFFFu) | (vb.z << 16);
        dst[base + 100] = (va.z >> 16)     | (vb.z & 0xFFFF0000u);
        dst[base + 120] = (va.w & 0xFFFFu) | (vb.w << 16);
        dst[base + 140] = (va.w >> 16)     | (vb.w & 0xFFFF0000u);
    }
    __syncthreads();

    const int m16 = lane & 15, quad = lane >> 4;
    const int t0 = wid * 32;

    // --- conv2 MFMA: packed tap pairs, 61 steps, 2 windows share bw ---
    f32x4 accA0 = {0,0,0,0}, accA1 = {0,0,0,0};
    f32x4 accB0 = {0,0,0,0}, accB1 = {0,0,0,0};
    const short* aptrA = hTA + (t0 + m16) * 40 + quad * 8;
    const short* aptrB = hTB + (t0 + m16) * 40 + quad * 8;
    s16x8 ringA[8], ringB[8];
#pragma unroll
    for (int j = 0; j < 8; ++j) {
        ringA[j] = *(const s16x8*)(aptrA + 2 * j * 40);
        ringB[j] = *(const s16x8*)(aptrB + 2 * j * 40);
    }
#pragma unroll
    for (int s = 0; s < 61; ++s) {
        const int k = s & 7;
        s16x8 bw  = *(const s16x8*)(w2f + s * 512 + lane * 8);
        s16x8 nwA = *(const s16x8*)(aptrA + (2 * s + 16) * 40);
        s16x8 nwB = *(const s16x8*)(aptrB + (2 * s + 16) * 40);
        accA0 = __builtin_amdgcn_mfma_f32_16x16x32_bf16(ringA[k], bw, accA0, 0, 0, 0);
        accA1 = __builtin_amdgcn_mfma_f32_16x16x32_bf16(nwA,      bw, accA1, 0, 0, 0);
        accB0 = __builtin_amdgcn_mfma_f32_16x16x32_bf16(ringB[k], bw, accB0, 0, 0, 0);
        accB1 = __builtin_amdgcn_mfma_f32_16x16x32_bf16(nwB,      bw, accB1, 0, 0, 0);
        ringA[k] = nwA;
        ringB[k] = nwB;
    }
    __syncthreads();   // hT data dead from here; overlays live

    // ---- fused epilogue, phase 1: E-pass stores + S init + latb pad ----
    if (m16 < 8) {
#pragma unroll
        for (int r = 0; r < 4; ++r) {
            latfA[m16 * 132 + t0 +      quad * 4 + r] = accA0[r];
            latfA[m16 * 132 + t0 + 16 + quad * 4 + r] = accA1[r];
            latfB[m16 * 132 + t0 +      quad * 4 + r] = accB0[r];
            latfB[m16 * 132 + t0 + 16 + quad * 4 + r] = accB1[r];
        }
    }
    if (tid < 8) { S0A[tid] = 0.0f; S1A[tid] = 0.0f; S0B[tid] = 0.0f; S1B[tid] = 0.0f; }
    if (tid < 64) {                                  // latb pad cols 121..127 = 0
        int e_ = tid >> 3, i = 121 + (tid & 7);
        if (i < 128) { latbA[e_ * 136 + i] = 0; latbB[e_ * 136 + i] = 0; }
    }
    __syncthreads();
    // ---- phase 2: O-pass (accumulate at i-1; distinct (e,i) per lane) ----
    if (m16 >= 8) {
        const int e_ = m16 - 8;
#pragma unroll
        for (int r = 0; r < 4; ++r) {
            int i0 = t0 + quad * 4 + r - 1;
            if (i0 >= 0) {
                latfA[e_ * 132 + i0] += accA0[r];
                latfB[e_ * 132 + i0] += accB0[r];
            }
            latfA[e_ * 132 + t0 + 15 + quad * 4 + r] += accA1[r];
            latfB[e_ * 132 + t0 + 15 + quad * 4 + r] += accB1[r];
        }
    }
    __syncthreads();
    // ---- phase 3: bias + bf16 mirror ----
    for (int idx = tid; idx < EMB * TLEN; idx += 256) {
        int e_ = idx / TLEN, i = idx - e_ * TLEN;
        float bb = b2[e_];
        float vA = latfA[e_ * 132 + i] + bb;
        float vB = latfB[e_ * 132 + i] + bb;
        latfA[e_ * 132 + i] = vA; latbA[e_ * 136 + i] = (short)f2bf(vA);
        latfB[e_ * 132 + i] = vB; latbB[e_ * 136 + i] = (short)f2bf(vB);
    }
    __syncthreads();
    // ---- phase 4: DFT via MFMA (A then B) + fc + bm ----
    {
        f32x4 aR = {0,0,0,0}, aI = {0,0,0,0};
        f32x4 bR = {0,0,0,0}, bI = {0,0,0,0};
#pragma unroll
        for (int ch = 0; ch < 4; ++ch) {
            s16x8 afrA = {0,0,0,0,0,0,0,0};
            s16x8 afrB = {0,0,0,0,0,0,0,0};
            if (m16 < 8) {
                afrA = *(const s16x8*)(latbA + m16 * 136 + quad * 8 + ch * 32);
                afrB = *(const s16x8*)(latbB + m16 * 136 + quad * 8 + ch * 32);
            }
            s16x8 br = *(const s16x8*)(w3f + (((ch * 8) + wid) * 64 + lane) * 8);
            s16x8 bi = *(const s16x8*)(w3f + (((ch * 8) + 4 + wid) * 64 + lane) * 8);
            aR = __builtin_amdgcn_mfma_f32_16x16x32_bf16(afrA, br, aR, 0, 0, 0);
            aI = __builtin_amdgcn_mfma_f32_16x16x32_bf16(afrA, bi, aI, 0, 0, 0);
            bR = __builtin_amdgcn_mfma_f32_16x16x32_bf16(afrB, br, bR, 0, 0, 0);
            bI = __builtin_amdgcn_mfma_f32_16x16x32_bf16(afrB, bi, bI, 0, 0, 0);
        }
        const int colj = m16;
        const int col  = wid * 16 + colj;
        const float fw = 0.5f * (float)(col + 1);
#pragma unroll
        for (int r = 0; r < 4; ++r) {
            float pwA = (col < 60) ? (aR[r] * aR[r] + aI[r] * aI[r]) : 0.0f;
            float s1A = pwA * fw;
            float pwB = (col < 60) ? (bR[r] * bR[r] + bI[r] * bI[r]) : 0.0f;
            float s1B = pwB * fw;
#pragma unroll
            for (int off = 1; off < 16; off <<= 1) {
                pwA += __shfl_xor(pwA, off);
                s1A += __shfl_xor(s1A, off);
                pwB += __shfl_xor(pwB, off);
                s1B += __shfl_xor(s1B, off);
            }
            if (colj == 0) {
                int e = quad * 4 + r;
                if (e < EMB) {
                    atomicAdd(&S0A[e], pwA); atomicAdd(&S1A[e], s1A);
                    atomicAdd(&S0B[e], pwB); atomicAdd(&S1B[e], s1B);
                }
            }
        }
    }
    if (tid < 128) {
        const int outi = tid >> 3, l8 = tid & 7;
        const int e_ = outi >> 1;
        const float* fr = fcw + outi * TLEN;
        float avA = 0.0f, avB = 0.0f;
        for (int t = l8; t < TLEN; t += 8) {
            float w = fr[t];
            avA += latfA[e_ * 132 + t] * w;
            avB += latfB[e_ * 132 + t] * w;
        }
        avA += __shfl_xor(avA, 1); avA += __shfl_xor(avA, 2); avA += __shfl_xor(avA, 4);
        avB += __shfl_xor(avB, 1); avB += __shfl_xor(avB, 2); avB += __shfl_xor(avB, 4);
        if (l8 == 0) { vvA[outi] = fcb[outi] + avA; vvB[outi] = fcb[outi] + avB; }
    } else if (tid < 192) {
        const int idx2 = tid - 128;
        const int e_ = idx2 >> 3, l8 = idx2 & 7;
        float sA = 0.0f, sB = 0.0f;
        for (int t = l8; t < TLEN; t += 8) {
            sA += latfA[e_ * 132 + t];
            sB += latfB[e_ * 132 + t];
        }
        sA += __shfl_xor(sA, 1); sA += __shfl_xor(sA, 2); sA += __shfl_xor(sA, 4);
        sB += __shfl_xor(sB, 1); sB += __shfl_xor(sB, 2); sB += __shfl_xor(sB, 4);
        if (l8 == 0) { bmA[e_] = sA * (1.0f / 121.0f); bmB[e_] = sB * (1.0f / 121.0f); }
    }
    __syncthreads();
    // ---- phase 5: final params + outputs ----
    if (tid < 8) {
        int e_ = tid;
        {
            float fv = S1A[e_] / S0A[e_];
            float av = 2.0f * sqrtf(S0A[e_]) * (1.0f / 121.0f);
            float pv = atan2f(vvA[2 * e_ + 1], vvA[2 * e_]) * 0.15915494309189535f;
            float bv = bmA[e_];
            int gi = (b * FULL + nA) * 8 + e_;
            pP[gi] = pv; pF[gi] = fv; pA[gi] = av; pB[gi] = bv;
            if (nA == 0) {
                oP[b * 8 + e_] = pv; oF[b * 8 + e_] = fv;
                oA[b * 8 + e_] = av; oB[b * 8 + e_] = bv;
            }
        }
        {
            float fv = S1B[e_] / S0B[e_];
            float av = 2.0f * sqrtf(S0B[e_]) * (1.0f / 121.0f);
            float pv = atan2f(vvB[2 * e_ + 1], vvB[2 * e_]) * 0.15915494309189535f;
            float bv = bmB[e_];
            int gi = (b * FULL + nB) * 8 + e_;
            pP[gi] = pv; pF[gi] = fv; pA[gi] = av; pB[gi] = bv;
        }
    }
    if (nA == 0) {
        for (int idx = tid; idx < EMB * TLEN; idx += 256) {
            int e_ = idx / TLEN, i = idx - e_ * TLEN;
            oLat[(b * EMB + e_) * TLEN + i] = latfA[e_ * 132 + i];
        }
    }
}

// ---------------------------------------------------------------------------
// k_sig_prep: fused k_signal (blocks 0..383) + k_prep_dec (blocks 384..1717).
// ---------------------------------------------------------------------------
__global__ __launch_bounds__(256) void k_sig_prep(
    const float* __restrict__ pP, const float* __restrict__ pF,
    const float* __restrict__ pA, const float* __restrict__ pB,
    float* __restrict__ sig, float* __restrict__ oSig,
    const float* __restrict__ dw1, const float* __restrict__ dw2,
    short* __restrict__ w1D, short* __restrict__ w2D)
{
    const int tid = threadIdx.x;
    if (blockIdx.x >= 384) {                 // ---- prep_dec part ----
        int gid = (blockIdx.x - 384) * 256 + tid;
        if (gid < 309760) {                                  // w2D
            int j = gid & 7, lane = (gid >> 3) & 63;
            int rest = gid >> 9;                             // m*5 + octile
            int ot = rest % 5, m = rest / 5;
            int oc = ot * 16 + (lane & 15);
            int c  = (lane >> 4) * 8 + j;
            float v = (oc < INCH && c < INTER) ? dw2[(oc * INTER + c) * TLEN + m] : 0.0f;
            w2D[gid] = (short)f2bf(v);
        } else if (gid < 341504) {                           // w1D
            int idx = gid - 309760;
            int j = idx & 7, lane = (idx >> 3) & 63;
            int rest = idx >> 9;                             // st*2 + octile
            int ot = rest & 1, st = rest >> 1;
            int oc = ot * 16 + (lane & 15);
            int m  = st * 4 + (lane >> 4);
            float v = (oc < INTER && m < TLEN) ? dw1[(oc * EMB + j) * TLEN + m] : 0.0f;
            w1D[idx] = (short)f2bf(v);
        }
        return;
    }
    // ---- signal part ----
    const int blk = blockIdx.x;          // (b*8 + e)*3 + uc
    const int uc = blk % 3;
    const int be = blk / 3;
    const int b = be >> 3, e = be & 7;
    __shared__ float sp[FULL], sf[FULL], sa[FULL], sb[FULL];
    for (int nn = tid; nn < FULL; nn += 256) {
        int gi = (b * FULL + nn) * 8 + e;
        sp[nn] = pP[gi]; sf[nn] = pF[gi]; sa[nn] = pA[gi]; sb[nn] = pB[gi];
    }
    __syncthreads();
    if (tid < 240) {
        const int u = uc * 120 + (tid >> 1);
        const int half = tid & 1;
        int nlo = (u - 120 > 0) ? (u - 120) : 0;
        int nhi = (u < 239) ? u : 239;
        int mid = (nlo + nhi + 1) >> 1;
        int lo = half ? mid : nlo;
        int hi = half ? nhi : (mid - 1);
        float s = 0.0f;
        for (int nn = lo; nn <= hi; ++nn) {
            float tt = (float)(u - nn);
            float z = sf[nn] * (tt * (1.0f / 60.0f) - 1.0f) + sp[nn];
            z -= floorf(z);
            s += sa[nn] * __builtin_amdgcn_sinf(z) + sb[nn];   // v_sin_f32 (rev)
        }
        s += __shfl_xor(s, 1);
        if (half == 0) {
            float wgt = (u < TLEN) ? (float)(u + 1) : ((u > 239) ? (float)(LP - u) : 121.0f);
            float val = s / wgt;
            sig[(b * EMB + e) * LP + u] = val;
            if (u < TLEN) oSig[(b * EMB + e) * TLEN + u] = val;
        }
    }
}

// ---------------------------------------------------------------------------
// k_dec1: decoder conv1 via MFMA. Block = (b, shalf) = 32 blocks. (round 15)
// ---------------------------------------------------------------------------
__global__ __launch_bounds__(256) void k_dec1(
    const float* __restrict__ sig, const short* __restrict__ w1D, const float* __restrict__ db1,
    float* __restrict__ dbuf, float* __restrict__ bns)
{
    const int blk = blockIdx.x;            // b*2 + shalf
    const int shalf = blk & 1, b = blk >> 1;
    const int tid = threadIdx.x;
    const int lane = tid & 63, wid = tid >> 6;
    __shared__ __align__(16) short yT[256 * 8];      // 4096 B (rows 248..255 stay 0)
    __shared__ float sS[INTER], sS2[INTER];

    if (tid < 256) ((uint4*)yT)[tid] = make_uint4(0, 0, 0, 0);
    if (tid < INTER) { sS[tid] = 0.0f; sS2[tid] = 0.0f; }
    __syncthreads();
    const int qbase = shalf * 120 - 60;
    for (int idx = tid; idx < 248 * 8; idx += 256) {
        int c = idx / 248, pos = idx - c * 248;
        int qy = qbase + pos;
        if (qy >= 0 && qy < FULL)
            yT[pos * 8 + c] = (short)f2bf(sig[(b * EMB + c) * LP + qy + 60]);
    }
    __syncthreads();

    const int col = lane & 15, quad = lane >> 4;
    f32x4 aA0 = {0,0,0,0}, aA1 = {0,0,0,0};   // stile wid   x octile 0/1
    f32x4 aB0 = {0,0,0,0}, aB1 = {0,0,0,0};   // stile wid+4 x octile 0/1
    const short* bb0 = yT + (wid * 16 + col + quad) * 8;
    const short* bb1 = yT + ((wid + 4) * 16 + col + quad) * 8;
#pragma unroll 4
    for (int st = 0; st < 31; ++st) {
        s16x8 a0 = *(const s16x8*)(w1D + ((st * 2 + 0) * 64 + lane) * 8);
        s16x8 a1 = *(const s16x8*)(w1D + ((st * 2 + 1) * 64 + lane) * 8);
        s16x8 b0 = *(const s16x8*)(bb0 + st * 32);
        s16x8 b1 = *(const s16x8*)(bb1 + st * 32);
        aA0 = __builtin_amdgcn_mfma_f32_16x16x32_bf16(a0, b0, aA0, 0, 0, 0);
        aA1 = __builtin_amdgcn_mfma_f32_16x16x32_bf16(a1, b0, aA1, 0, 0, 0);
        aB0 = __builtin_amdgcn_mfma_f32_16x16x32_bf16(a0, b1, aB0, 0, 0, 0);
        aB1 = __builtin_amdgcn_mfma_f32_16x16x32_bf16(a1, b1, aB1, 0, 0, 0);
    }

    // epilogue: bias + store dbuf + masked stats (col-reduce then LDS atomics)
#pragma unroll
    for (int half = 0; half < 2; ++half) {
        const int sl_base = (wid + half * 4) * 16;
#pragma unroll
        for (int ot = 0; ot < 2; ++ot) {
            f32x4 acc = (half == 0) ? (ot == 0 ? aA0 : aA1) : (ot == 0 ? aB0 : aB1);
#pragma unroll
            for (int r = 0; r < 4; ++r) {
                int oc = ot * 16 + quad * 4 + r;
                int sl = sl_base + col;
                float val = 0.0f;
                if (oc < INTER && sl < 120) {
                    val = acc[r] + db1[oc];
                    dbuf[(b * INTER + oc) * FULL + shalf * 120 + sl] = val;
                }
                float s1 = val, s2 = val * val;
                s1 += __shfl_xor(s1, 1); s2 += __shfl_xor(s2, 1);
                s1 += __shfl_xor(s1, 2); s2 += __shfl_xor(s2, 2);
                s1 += __shfl_xor(s1, 4); s2 += __shfl_xor(s2, 4);
                s1 += __shfl_xor(s1, 8); s2 += __shfl_xor(s2, 8);
                if (col == 0 && oc < INTER) {
                    atomicAdd(&sS[oc], s1);
                    atomicAdd(&sS2[oc], s2);
                }
            }
        }
    }
    __syncthreads();
    if (tid < INTER) {
        atomicAdd(&bns[tid], sS[tid]);
        atomicAdd(&bns[24 + tid], sS2[tid]);
    }
}

// ---------------------------------------------------------------------------
// k_dec2: decoder conv2 via MFMA with fused BN+tanh staging. (round 15 +
// round 27: fast_tanh)
// ---------------------------------------------------------------------------
__global__ __launch_bounds__(256) void k_dec2(
    const float* __restrict__ dbuf, const float* __restrict__ bns,
    const float* __restrict__ gma, const float* __restrict__ bta,
    const short* __restrict__ w2D, const float* __restrict__ db2,
    float* __restrict__ oY, float* __restrict__ oYp)
{
    const int blk = blockIdx.x;            // (b*2 + shalf)*5 + octile
    const int octile = blk % 5;
    const int bh = blk / 5;
    const int shalf = bh & 1, b = bh >> 1;
    const int tid = threadIdx.x;
    const int lane = tid & 63, wid = tid >> 6;
    __shared__ __align__(16) short dT[248 * 40];     // 19840 B
    __shared__ float scl[INTER], sft[INTER];

    if (tid < INTER) {
        float m  = bns[tid] * (1.0f / 3840.0f);
        float v  = bns[24 + tid] * (1.0f / 3840.0f) - m * m;
        float rs = rsqrtf(fmaxf(v, 0.0f) + 1e-5f);
        float g  = gma[tid];
        scl[tid] = rs * g;
        sft[tid] = bta[tid] - m * rs * g;
    }
    for (int idx = tid; idx < 1240; idx += 256) ((uint4*)dT)[idx] = make_uint4(0,0,0,0);
    __syncthreads();
    const int qbase = shalf * 120 - 60;
    for (int idx = tid; idx < 248 * 24; idx += 256) {
        int c = idx / 248, pos = idx - c * 248;
        int qy = qbase + pos;
        if (qy >= 0 && qy < FULL) {
            float v = fast_tanh(dbuf[(b * INTER + c) * FULL + qy] * scl[c] + sft[c]);
            dT[pos * 40 + c] = (short)f2bf(v);
        }
    }
    __syncthreads();

    const int col = lane & 15, quad = lane >> 4;
    f32x4 acc0 = {0,0,0,0}, acc1 = {0,0,0,0};
    const short* bb0 = dT + (wid * 16 + col) * 40 + quad * 8;
    const short* bb1 = dT + ((wid + 4) * 16 + col) * 40 + quad * 8;
    const short* ab  = w2D + (octile * 64 + lane) * 8;
#pragma unroll 8
    for (int m = 0; m < TLEN; ++m) {
        s16x8 af = *(const s16x8*)(ab + m * 2560);       // 5*512 shorts per tap
        s16x8 b0 = *(const s16x8*)(bb0 + m * 40);
        s16x8 b1 = *(const s16x8*)(bb1 + m * 40);
        acc0 = __builtin_amdgcn_mfma_f32_16x16x32_bf16(af, b0, acc0, 0, 0, 0);
        acc1 = __builtin_amdgcn_mfma_f32_16x16x32_bf16(af, b1, acc1, 0, 0, 0);
    }

#pragma unroll
    for (int r = 0; r < 4; ++r) {
        int oc = octile * 16 + quad * 4 + r;
        if (oc < INCH) {
            float bias = db2[oc];
            {
                int sl = wid * 16 + col;                 // <= 63, always valid
                int sg = shalf * 120 + sl;
                float v = acc0[r] + bias;
                oY[(b * INCH + oc) * FULL + sg] = v;
                if (sg < TLEN) oYp[(b * INCH + oc) * TLEN + sg] = v;
            }
            {
                int sl = (wid + 4) * 16 + col;
                if (sl < 120) {
                    int sg = shalf * 120 + sl;
                    float v = acc1[r] + bias;
                    oY[(b * INCH + oc) * FULL + sg] = v;
                    if (sg < TLEN) oYp[(b * INCH + oc) * TLEN + sg] = v;
                }
            }
        }
    }
}

// ---------------------------------------------------------------------------
extern "C" void kernel_launch(void* const* d_in, const int* in_sizes, int n_in,
                              void* d_out, int out_size, void* d_ws, size_t ws_size,
                              hipStream_t stream)
{
    const float* x   = (const float*)d_in[0];
    const float* w1  = (const float*)d_in[1];
    const float* b1  = (const float*)d_in[2];
    const float* lna = (const float*)d_in[3];
    const float* lnb = (const float*)d_in[4];
    const float* w2  = (const float*)d_in[5];
    const float* b2  = (const float*)d_in[6];
    const float* fcw = (const float*)d_in[7];
    const float* fcb = (const float*)d_in[8];
    const float* dw1 = (const float*)d_in[9];
    const float* db1 = (const float*)d_in[10];
    const float* gma = (const float*)d_in[11];
    const float* bta = (const float*)d_in[12];
    const float* dw2 = (const float*)d_in[13];
    const float* db2 = (const float*)d_in[14];

    // Output layout (flat fp32, reference return order):
    float* out  = (float*)d_out;
    float* oY   = out;                 // [16][72][240]
    float* oLat = out + 276480;        // [16][8][121]
    float* oSig = out + 291968;        // [16][8][121]
    float* oP   = out + 307456;
    float* oF   = out + 307584;
    float* oA   = out + 307712;
    float* oB   = out + 307840;
    float* oYp  = out + 307968;        // [16][72][121]

    // Workspace layout (bytes): unchanged from round 22/25.
    short* w2f  = (short*)d_ws;
    short* w3f  = (short*)((char*)d_ws + 123904);
    short* w1fA = (short*)((char*)d_ws + 156672);
    float* fb   = (float*)((char*)d_ws + 900096);
    float* pP   = fb;
    float* pF   = pP + 30720;
    float* pA   = pF + 30720;
    float* pB   = pA + 30720;
    float* dbuf = fb;                  // overlay (temporally disjoint)
    float* sig  = fb + 122880;         // 46080
    float* bns  = sig + 46080;         // 48
    float* Q    = (float*)((char*)d_ws + 1576128);
    short* w2D  = (short*)((char*)d_ws + 1576128);            // Q overlay
    short* w1D  = (short*)((char*)d_ws + 1576128 + 619520);   // Q overlay

    k_prep_all<<<1644, 256, 0, stream>>>(w2, w1, w2f, w3f, w1fA, bns);
    k_q<<<512, 256, 0, stream>>>(x, w1fA, Q);
    k_prefix_ln<<<384, 256, 0, stream>>>(Q, b1, lna, lnb);
    k_enc2<<<1920, 256, 0, stream>>>(Q, w2f, w3f, b2, fcw, fcb,
                                     pP, pF, pA, pB, oLat, oP, oF, oA, oB);
    k_sig_prep<<<1718, 256, 0, stream>>>(pP, pF, pA, pB, sig, oSig,
                                         dw1, dw2, w1D, w2D);
    k_dec1<<<32, 256, 0, stream>>>(sig, w1D, db1, dbuf, bns);
    k_dec2<<<160, 256, 0, stream>>>(dbuf, bns, gma, bta, w2D, db2, oY, oYp);
}

// Round 18
// 232.467 us; speedup vs baseline: 1.2803x; 1.0035x over previous
//
#include <hip/hip_runtime.h>
#include <math.h>

// ---------------------------------------------------------------------------
// PAE pipeline on MI355X. Round 31 == verified round 27 (233.3us).
//   ROOT CAUSE of r28/r29/r30 failures found: the k_enc2 zero-init "trim"
//   zeroed pad ROWS only, but staging writes only channels 0..23 of rows
//   60..187 -- pad CHANNELS 24..39 (read by quad=3 MFMA B-fragments) were
//   left as stale LDS garbage. Cooperative launch was wrongly blamed (r30
//   failed identically without it). Full 1240-uint4 zero-init restored;
//   source is byte-identical to round 27.
// ---------------------------------------------------------------------------

#define INCH   72
#define TLEN   121
#define FULL   240
#define INTER  24
#define EMB    8
#define LP     360
#define NWIN   3840

typedef __attribute__((ext_vector_type(8)))  short s16x8;
typedef __attribute__((ext_vector_type(4)))  float f32x4;

__device__ __forceinline__ unsigned short f2bf(float f) {
    unsigned u = __float_as_uint(f);
    unsigned r = ((u >> 16) & 1u) + 0x7FFFu;
    return (unsigned short)((u + r) >> 16);
}
__device__ __forceinline__ float bf2f(unsigned short u) {
    return __uint_as_float((unsigned)u << 16);
}
__device__ __forceinline__ float fast_tanh(float x) {
    float cx = fminf(fmaxf(x, -15.0f), 15.0f);
    float t  = __builtin_amdgcn_exp2f(cx * 2.8853900817779268f);  // 2*log2(e)
    return (t - 1.0f) * __builtin_amdgcn_rcpf(t + 1.0f);
}

// ---------------------------------------------------------------------------
// k_prep_all: w2f | w3f | w1fA in one launch + bns zero (round 26).
// ---------------------------------------------------------------------------
__global__ __launch_bounds__(256) void k_prep_all(
    const float* __restrict__ w2, const float* __restrict__ w1,
    short* __restrict__ w2f, short* __restrict__ w3f, short* __restrict__ w1fA,
    float* __restrict__ bns)
{
    int gid = blockIdx.x * 256 + threadIdx.x;
    if (gid < 48) bns[gid] = 0.0f;                       // replaces memset
    if (gid < 32768) {                                   // w2f (packed pairs, 64 frags)
        int idx = gid;
        int j = idx & 7, ln = (idx >> 3) & 63, s = idx >> 9;   // s 0..63
        int nn = ln & 15, c = (ln >> 4) * 8 + j;
        int e = nn & 7;
        int tap = 2 * s + (nn >> 3);
        float v = (c < INTER && tap <= 120) ? w2[(e * INTER + c) * TLEN + tap] : 0.0f;
        w2f[idx] = (short)f2bf(v);
    } else if (gid < 49152) {                            // w3f
        int idx = gid - 32768;
        int j = idx & 7, ln = (idx >> 3) & 63, tl = (idx >> 9) & 7, ch = idx >> 12;
        int t = (ln >> 4) * 8 + j + ch * 32;
        int colIdx = (tl & 3) * 16 + (ln & 15);
        int k = colIdx + 1;
        float v = 0.0f;
        if (t < TLEN && colIdx < 60) {
            int mm = (k * t) % 121;
            float rev = (float)mm * (1.0f / 121.0f);     // revolutions
            float s = __builtin_amdgcn_sinf(rev);        // v_sin_f32
            float c = __builtin_amdgcn_cosf(rev);        // v_cos_f32
            v = (tl < 4) ? c : -s;
        }
        w3f[idx] = (short)f2bf(v);
    } else if (gid < 420864) {                           // w1fA
        int idx = gid - 49152;
        int j = idx & 7, ln = (idx >> 3) & 63;
        int rest = idx >> 9;
        int ch = rest % 3;
        int rest2 = rest / 3;
        int ot = rest2 & 1, tap = rest2 >> 1;
        int o = ot * 16 + (ln & 15);
        int c = (ln >> 4) * 8 + j + ch * 32;
        float v = (o < INTER && c < INCH) ? w1[(o * INCH + c) * TLEN + tap] : 0.0f;
        w1fA[idx] = (short)f2bf(v);
    }
}

// ---------------------------------------------------------------------------
// k_q: Q[b][o][m][s] = sum_c w1[o,c,m] * x[b,c,(s+m)%240] via MFMA.
// (round 22 verified: A = x rows=s, B = w1 cols=o -> float4 stores; grid 512)
// ---------------------------------------------------------------------------
__global__ __launch_bounds__(256) void k_q(
    const float* __restrict__ x, const short* __restrict__ w1fA,
    float* __restrict__ Q)
{
    const int blk = blockIdx.x;
    const int mg2 = blk & 15, sh = (blk >> 4) & 1, b = blk >> 5;
    const int tid = threadIdx.x;
    const int lane = tid & 63, wid = tid >> 6;
    const int s0 = sh * 120;
    __shared__ __align__(16) short xTb[248 * 104];   // 51584 B

    for (int idx = tid; idx < (248 * 104) / 8; idx += 256)
        ((uint4*)xTb)[idx] = make_uint4(0, 0, 0, 0);
    __syncthreads();
    for (int idx = tid; idx < 72 * 248; idx += 256) {
        int c = idx / 248, l = idx - c * 248;
        int g = s0 + l; g -= (g >= FULL) ? FULL : 0;
        xTb[l * 104 + c] = (short)f2bf(x[(b * INCH + c) * FULL + g]);
    }
    __syncthreads();

    const int ntaps = (mg2 < 15) ? 8 : 1;            // taps 120 only in group 15
    const int m16 = lane & 15, quad = lane >> 4;
    for (int j = 0; j < ntaps; ++j) {
        const int m = mg2 * 8 + j;
        s16x8 bw[2][3];                              // w1 B-fragments (cols=o)
#pragma unroll
        for (int ot = 0; ot < 2; ++ot)
#pragma unroll
            for (int ch = 0; ch < 3; ++ch)
                bw[ot][ch] = *(const s16x8*)(w1fA + (((m * 2 + ot) * 3 + ch) * 64 + lane) * 8);
#pragma unroll
        for (int tt = 0; tt < 2; ++tt) {
            const int ts = (wid + tt * 4) * 16;      // s-tile base
            const short* arow = xTb + (ts + m16 + m) * 104 + quad * 8;
            s16x8 a0 = *(const s16x8*)(arow);        // A rows = s, k = c
            s16x8 a1 = *(const s16x8*)(arow + 32);
            s16x8 a2 = *(const s16x8*)(arow + 64);
#pragma unroll
            for (int ot = 0; ot < 2; ++ot) {
                f32x4 acc = {0.0f, 0.0f, 0.0f, 0.0f};
                acc = __builtin_amdgcn_mfma_f32_16x16x32_bf16(a0, bw[ot][0], acc, 0, 0, 0);
                acc = __builtin_amdgcn_mfma_f32_16x16x32_bf16(a1, bw[ot][1], acc, 0, 0, 0);
                acc = __builtin_amdgcn_mfma_f32_16x16x32_bf16(a2, bw[ot][2], acc, 0, 0, 0);
                const int o = ot * 16 + m16;         // C col = o
                if (o < INTER) {
                    const int sbase = ts + quad * 4; // C row = s
                    float* qp = Q + ((size_t)(b * INTER + o) * TLEN + m) * FULL + s0 + sbase;
                    if (sbase + 3 < 120) {
                        *(float4*)qp = make_float4(acc[0], acc[1], acc[2], acc[3]);
                    } else {
#pragma unroll
                        for (int r = 0; r < 4; ++r)
                            if (sbase + r < 120) qp[r] = acc[r];
                    }
                }
            }
        }
    }
}

// ---------------------------------------------------------------------------
// k_prefix_ln: fused prefix + conv1-diff + LN + tanh -> bf16 h3 overlay.
// (round 21/22 verified form; round 27: fast_tanh in pass-2)
// ---------------------------------------------------------------------------
__global__ __launch_bounds__(256) void k_prefix_ln(
    float* __restrict__ Q, const float* __restrict__ b1,
    const float* __restrict__ lna, const float* __restrict__ lnb)
{
    const int blk = blockIdx.x;          // b*24 + o
    const int o = blk % INTER;
    const int tid = threadIdx.x;
    __shared__ float r121[FULL];                              // 960 B
    __shared__ __align__(16) unsigned short hls[FULL * TLEN]; // 58080 B
    float* Rg = Q + (size_t)blk * (TLEN * FULL);

    // --- prefix phase: in-place inclusive prefix over taps, col = tid ---
    if (tid < FULL) {
        float* Qc = Rg + tid;
        float P = 0.0f;
        for (int m = 0; m < 120; m += 4) {
            float q0 = Qc[m * FULL];
            float q1 = Qc[(m + 1) * FULL];
            float q2 = Qc[(m + 2) * FULL];
            float q3 = Qc[(m + 3) * FULL];
            P += q0; Qc[m * FULL]       = P;
            P += q1; Qc[(m + 1) * FULL] = P;
            P += q2; Qc[(m + 2) * FULL] = P;
            P += q3; Qc[(m + 3) * FULL] = P;
        }
        P += Qc[120 * FULL];
        Qc[120 * FULL] = P;              // row 120 = R[121]
        r121[tid] = P;                   // register -> LDS, no re-read
    }
    __syncthreads();

    if (tid < FULL) {
        const int n = tid;
        const float bias = b1[o];
        unsigned short* hrow = hls + n * TLEN;
        float s = 0.0f, s2 = 0.0f;
        // pass 1: compute v, cache bf16(v), accumulate stats (fp32 v)
        for (int i = 0; i < 60; ++i) {                   // lo = 60-i >= 1
            int st = n + i - 120; st += (st < 0) ? FULL : 0;
            float v = r121[st] - Rg[(59 - i) * FULL + st] + bias;
            s += v; s2 += v * v;
            hrow[i] = f2bf(v);
        }
        {                                                // i = 60: lo = 0
            int st = n - 60; st += (st < 0) ? FULL : 0;
            float v = r121[st] + bias;
            s += v; s2 += v * v;
            hrow[60] = f2bf(v);
        }
        for (int i = 61; i < TLEN; ++i) {                // up = 181-i, lo = 0
            int st = n + i - 120; st += (st < 0) ? FULL : 0;
            float v = Rg[(180 - i) * FULL + st] + bias;
            s += v; s2 += v * v;
            hrow[i] = f2bf(v);
        }
        float mean = s * (1.0f / 121.0f);
        float var  = fmaxf((s2 - s * mean) * (1.0f / 120.0f), 0.0f);   // ddof=1
        float inv  = 1.0f / (sqrtf(var) + 1e-5f);                      // (std+eps)
        // pass 2: LDS-only transform + tanh
        for (int i = 0; i < TLEN; ++i) {
            float v = bf2f(hrow[i]);
            v = (v - mean) * inv * lna[i] + lnb[i];
            hrow[i] = f2bf(fast_tanh(v));
        }
    }
    __syncthreads();
    // dump: repack stride-121 LDS rows -> [240][128] global ushort rows
    {
        unsigned short* dstg = (unsigned short*)Rg;
        for (int idx = tid; idx < 3840; idx += 256) {
            int row = idx >> 4, c = idx & 15;
            const unsigned short* src = hls + row * TLEN + c * 8;
            unsigned v0, v1, v2, v3;
            if (c < 15) {
                v0 = (unsigned)src[0] | ((unsigned)src[1] << 16);
                v1 = (unsigned)src[2] | ((unsigned)src[3] << 16);
                v2 = (unsigned)src[4] | ((unsigned)src[5] << 16);
                v3 = (unsigned)src[6] | ((unsigned)src[7] << 16);
            } else {                     // shorts 120..127: only 120 is real
                v0 = (unsigned)src[0];
                v1 = 0; v2 = 0; v3 = 0;
            }
            uint4 v = make_uint4(v0, v1, v2, v3);
            *(uint4*)(dstg + row * 128 + c * 8) = v;
        }
    }
}

// ---------------------------------------------------------------------------
// k_enc2: 2-window conv2 MFMA (shared w2f B-fragments) + FUSED epilogue.
// FULL zero-init (1240 uint4 per buffer) -- pad channels 24..39 of all rows
// must be zero for the K=32 MFMA B-fragments (quad=3 reads shorts 24..31).
// Block = (b, nb) -> windows {2nb, 2nb+1}. Grid 1920.
// ---------------------------------------------------------------------------
__global__ __launch_bounds__(256, 4) void k_enc2(
    const float* __restrict__ Q, const short* __restrict__ w2f,
    const short* __restrict__ w3f, const float* __restrict__ b2,
    const float* __restrict__ fcw, const float* __restrict__ fcb,
    float* __restrict__ pP, float* __restrict__ pF, float* __restrict__ pA, float* __restrict__ pB,
    float* __restrict__ oLat, float* __restrict__ oP, float* __restrict__ oF,
    float* __restrict__ oA, float* __restrict__ oB)
{
    const int blk = blockIdx.x;          // b*120 + nb
    const int b   = blk / 120, nb = blk - b * 120;
    const int nA  = 2 * nb, nB = 2 * nb + 1;
    const int tid = threadIdx.x;
    const int lane = tid & 63, wid = tid >> 6;

    __shared__ __align__(16) short hTA[248 * 40];    // 19840 B
    __shared__ __align__(16) short hTB[248 * 40];    // 19840 B
    // epilogue overlays (hT buffers dead after conv loop):
    float* latfA = (float*)hTA;                      // [EMB*132]  4224 B
    short* latbA = (short*)((char*)hTA + 4224);      // [EMB*136]  2176 B
    float* S0A   = (float*)((char*)hTA + 6400);
    float* S1A   = (float*)((char*)hTA + 6432);
    float* vvA   = (float*)((char*)hTA + 6464);
    float* bmA   = (float*)((char*)hTA + 6528);
    float* latfB = (float*)hTB;
    short* latbB = (short*)((char*)hTB + 4224);
    float* S0B   = (float*)((char*)hTB + 6400);
    float* S1B   = (float*)((char*)hTB + 6432);
    float* vvB   = (float*)((char*)hTB + 6464);
    float* bmB   = (float*)((char*)hTB + 6528);

    for (int idx = tid; idx < 1240; idx += 256) {
        ((uint4*)hTA)[idx] = make_uint4(0,0,0,0);
        ((uint4*)hTB)[idx] = make_uint4(0,0,0,0);
    }
    __syncthreads();

    // staging: item = (win, u4, channel-pair op). Each thread loads 2 uint4
    // (channels 2op, 2op+1; 8 consecutive i) and writes 8 packed dwords to
    // hT[(60+u4*8+k)*40 + 2op..2op+1]. Covers rows 60..187, channels 0..23.
    for (int idx = tid; idx < 384; idx += 256) {
        int win = (idx >= 192);
        int rem = idx - win * 192;
        int op = rem % 12, u4 = rem / 12;            // op 0..11, u4 0..15
        int n = win ? nB : nA;
        const unsigned short* h3a =
            (const unsigned short*)(Q + (size_t)(b * INTER + 2 * op) * (TLEN * FULL));
        const unsigned short* h3b =
            (const unsigned short*)(Q + (size_t)(b * INTER + 2 * op + 1) * (TLEN * FULL));
        uint4 va = *(const uint4*)(h3a + n * 128 + u4 * 8);
        uint4 vb = *(const uint4*)(h3b + n * 128 + u4 * 8);
        unsigned* dst = (unsigned*)(win ? hTB : hTA);
        int base = (60 + u4 * 8) * 20 + op;          // dword offset
        dst[base +   0] = (va.x & 0xFFFFu) | (vb.x << 16);
        dst[base +  20] = (va.x >> 16)     | (vb.x & 0xFFFF0000u);
        dst[base +  40] = (va.y & 0xFFFFu) | (vb.y << 16);
        dst[base +  60] = (va.y >> 16)     | (vb.y & 0xFFFF0000u);
        dst[base +  80] = (va.z & 0xFFFFu) | (vb.z << 16);
        dst[base + 100] = (va.z >> 16)     | (vb.z & 0xFFFF0000u);
        dst[base + 120] = (va.w & 0xFFFFu) | (vb.w << 16);
        dst[base + 140] = (va.w >> 16)     | (vb.w & 0xFFFF0000u);
    }
    __syncthreads();

    const int m16 = lane & 15, quad = lane >> 4;
    const int t0 = wid * 32;

    // --- conv2 MFMA: packed tap pairs, 61 steps, 2 windows share bw ---
    f32x4 accA0 = {0,0,0,0}, accA1 = {0,0,0,0};
    f32x4 accB0 = {0,0,0,0}, accB1 = {0,0,0,0};
    const short* aptrA = hTA + (t0 + m16) * 40 + quad * 8;
    const short* aptrB = hTB + (t0 + m16) * 40 + quad * 8;
    s16x8 ringA[8], ringB[8];
#pragma unroll
    for (int j = 0; j < 8; ++j) {
        ringA[j] = *(const s16x8*)(aptrA + 2 * j * 40);
        ringB[j] = *(const s16x8*)(aptrB + 2 * j * 40);
    }
#pragma unroll
    for (int s = 0; s < 61; ++s) {
        const int k = s & 7;
        s16x8 bw  = *(const s16x8*)(w2f + s * 512 + lane * 8);
        s16x8 nwA = *(const s16x8*)(aptrA + (2 * s + 16) * 40);
        s16x8 nwB = *(const s16x8*)(aptrB + (2 * s + 16) * 40);
        accA0 = __builtin_amdgcn_mfma_f32_16x16x32_bf16(ringA[k], bw, accA0, 0, 0, 0);
        accA1 = __builtin_amdgcn_mfma_f32_16x16x32_bf16(nwA,      bw, accA1, 0, 0, 0);
        accB0 = __builtin_amdgcn_mfma_f32_16x16x32_bf16(ringB[k], bw, accB0, 0, 0, 0);
        accB1 = __builtin_amdgcn_mfma_f32_16x16x32_bf16(nwB,      bw, accB1, 0, 0, 0);
        ringA[k] = nwA;
        ringB[k] = nwB;
    }
    __syncthreads();   // hT data dead from here; overlays live

    // ---- fused epilogue, phase 1: E-pass stores + S init + latb pad ----
    if (m16 < 8) {
#pragma unroll
        for (int r = 0; r < 4; ++r) {
            latfA[m16 * 132 + t0 +      quad * 4 + r] = accA0[r];
            latfA[m16 * 132 + t0 + 16 + quad * 4 + r] = accA1[r];
            latfB[m16 * 132 + t0 +      quad * 4 + r] = accB0[r];
            latfB[m16 * 132 + t0 + 16 + quad * 4 + r] = accB1[r];
        }
    }
    if (tid < 8) { S0A[tid] = 0.0f; S1A[tid] = 0.0f; S0B[tid] = 0.0f; S1B[tid] = 0.0f; }
    if (tid < 64) {                                  // latb pad cols 121..127 = 0
        int e_ = tid >> 3, i = 121 + (tid & 7);
        if (i < 128) { latbA[e_ * 136 + i] = 0; latbB[e_ * 136 + i] = 0; }
    }
    __syncthreads();
    // ---- phase 2: O-pass (accumulate at i-1; distinct (e,i) per lane) ----
    if (m16 >= 8) {
        const int e_ = m16 - 8;
#pragma unroll
        for (int r = 0; r < 4; ++r) {
            int i0 = t0 + quad * 4 + r - 1;
            if (i0 >= 0) {
                latfA[e_ * 132 + i0] += accA0[r];
                latfB[e_ * 132 + i0] += accB0[r];
            }
            latfA[e_ * 132 + t0 + 15 + quad * 4 + r] += accA1[r];
            latfB[e_ * 132 + t0 + 15 + quad * 4 + r] += accB1[r];
        }
    }
    __syncthreads();
    // ---- phase 3: bias + bf16 mirror ----
    for (int idx = tid; idx < EMB * TLEN; idx += 256) {
        int e_ = idx / TLEN, i = idx - e_ * TLEN;
        float bb = b2[e_];
        float vA = latfA[e_ * 132 + i] + bb;
        float vB = latfB[e_ * 132 + i] + bb;
        latfA[e_ * 132 + i] = vA; latbA[e_ * 136 + i] = (short)f2bf(vA);
        latfB[e_ * 132 + i] = vB; latbB[e_ * 136 + i] = (short)f2bf(vB);
    }
    __syncthreads();
    // ---- phase 4: DFT via MFMA (A then B) + fc + bm ----
    {
        f32x4 aR = {0,0,0,0}, aI = {0,0,0,0};
        f32x4 bR = {0,0,0,0}, bI = {0,0,0,0};
#pragma unroll
        for (int ch = 0; ch < 4; ++ch) {
            s16x8 afrA = {0,0,0,0,0,0,0,0};
            s16x8 afrB = {0,0,0,0,0,0,0,0};
            if (m16 < 8) {
                afrA = *(const s16x8*)(latbA + m16 * 136 + quad * 8 + ch * 32);
                afrB = *(const s16x8*)(latbB + m16 * 136 + quad * 8 + ch * 32);
            }
            s16x8 br = *(const s16x8*)(w3f + (((ch * 8) + wid) * 64 + lane) * 8);
            s16x8 bi = *(const s16x8*)(w3f + (((ch * 8) + 4 + wid) * 64 + lane) * 8);
            aR = __builtin_amdgcn_mfma_f32_16x16x32_bf16(afrA, br, aR, 0, 0, 0);
            aI = __builtin_amdgcn_mfma_f32_16x16x32_bf16(afrA, bi, aI, 0, 0, 0);
            bR = __builtin_amdgcn_mfma_f32_16x16x32_bf16(afrB, br, bR, 0, 0, 0);
            bI = __builtin_amdgcn_mfma_f32_16x16x32_bf16(afrB, bi, bI, 0, 0, 0);
        }
        const int colj = m16;
        const int col  = wid * 16 + colj;
        const float fw = 0.5f * (float)(col + 1);
#pragma unroll
        for (int r = 0; r < 4; ++r) {
            float pwA = (col < 60) ? (aR[r] * aR[r] + aI[r] * aI[r]) : 0.0f;
            float s1A = pwA * fw;
            float pwB = (col < 60) ? (bR[r] * bR[r] + bI[r] * bI[r]) : 0.0f;
            float s1B = pwB * fw;
#pragma unroll
            for (int off = 1; off < 16; off <<= 1) {
                pwA += __shfl_xor(pwA, off);
                s1A += __shfl_xor(s1A, off);
                pwB += __shfl_xor(pwB, off);
                s1B += __shfl_xor(s1B, off);
            }
            if (colj == 0) {
                int e = quad * 4 + r;
                if (e < EMB) {
                    atomicAdd(&S0A[e], pwA); atomicAdd(&S1A[e], s1A);
                    atomicAdd(&S0B[e], pwB); atomicAdd(&S1B[e], s1B);
                }
            }
        }
    }
    if (tid < 128) {
        const int outi = tid >> 3, l8 = tid & 7;
        const int e_ = outi >> 1;
        const float* fr = fcw + outi * TLEN;
        float avA = 0.0f, avB = 0.0f;
        for (int t = l8; t < TLEN; t += 8) {
            float w = fr[t];
            avA += latfA[e_ * 132 + t] * w;
            avB += latfB[e_ * 132 + t] * w;
        }
        avA += __shfl_xor(avA, 1); avA += __shfl_xor(avA, 2); avA += __shfl_xor(avA, 4);
        avB += __shfl_xor(avB, 1); avB += __shfl_xor(avB, 2); avB += __shfl_xor(avB, 4);
        if (l8 == 0) { vvA[outi] = fcb[outi] + avA; vvB[outi] = fcb[outi] + avB; }
    } else if (tid < 192) {
        const int idx2 = tid - 128;
        const int e_ = idx2 >> 3, l8 = idx2 & 7;
        float sA = 0.0f, sB = 0.0f;
        for (int t = l8; t < TLEN; t += 8) {
            sA += latfA[e_ * 132 + t];
            sB += latfB[e_ * 132 + t];
        }
        sA += __shfl_xor(sA, 1); sA += __shfl_xor(sA, 2); sA += __shfl_xor(sA, 4);
        sB += __shfl_xor(sB, 1); sB += __shfl_xor(sB, 2); sB += __shfl_xor(sB, 4);
        if (l8 == 0) { bmA[e_] = sA * (1.0f / 121.0f); bmB[e_] = sB * (1.0f / 121.0f); }
    }
    __syncthreads();
    // ---- phase 5: final params + outputs ----
    if (tid < 8) {
        int e_ = tid;
        {
            float fv = S1A[e_] / S0A[e_];
            float av = 2.0f * sqrtf(S0A[e_]) * (1.0f / 121.0f);
            float pv = atan2f(vvA[2 * e_ + 1], vvA[2 * e_]) * 0.15915494309189535f;
            float bv = bmA[e_];
            int gi = (b * FULL + nA) * 8 + e_;
            pP[gi] = pv; pF[gi] = fv; pA[gi] = av; pB[gi] = bv;
            if (nA == 0) {
                oP[b * 8 + e_] = pv; oF[b * 8 + e_] = fv;
                oA[b * 8 + e_] = av; oB[b * 8 + e_] = bv;
            }
        }
        {
            float fv = S1B[e_] / S0B[e_];
            float av = 2.0f * sqrtf(S0B[e_]) * (1.0f / 121.0f);
            float pv = atan2f(vvB[2 * e_ + 1], vvB[2 * e_]) * 0.15915494309189535f;
            float bv = bmB[e_];
            int gi = (b * FULL + nB) * 8 + e_;
            pP[gi] = pv; pF[gi] = fv; pA[gi] = av; pB[gi] = bv;
        }
    }
    if (nA == 0) {
        for (int idx = tid; idx < EMB * TLEN; idx += 256) {
            int e_ = idx / TLEN, i = idx - e_ * TLEN;
            oLat[(b * EMB + e_) * TLEN + i] = latfA[e_ * 132 + i];
        }
    }
}

// ---------------------------------------------------------------------------
// k_sig_prep: fused k_signal (blocks 0..383) + k_prep_dec (blocks 384..1717).
// (round 26/27 verified form)
// ---------------------------------------------------------------------------
__global__ __launch_bounds__(256) void k_sig_prep(
    const float* __restrict__ pP, const float* __restrict__ pF,
    const float* __restrict__ pA, const float* __restrict__ pB,
    float* __restrict__ sig, float* __restrict__ oSig,
    const float* __restrict__ dw1, const float* __restrict__ dw2,
    short* __restrict__ w1D, short* __restrict__ w2D)
{
    const int tid = threadIdx.x;
    if (blockIdx.x >= 384) {                 // ---- prep_dec part ----
        int gid = (blockIdx.x - 384) * 256 + tid;
        if (gid < 309760) {                                  // w2D
            int j = gid & 7, lane = (gid >> 3) & 63;
            int rest = gid >> 9;                             // m*5 + octile
            int ot = rest % 5, m = rest / 5;
            int oc = ot * 16 + (lane & 15);
            int c  = (lane >> 4) * 8 + j;
            float v = (oc < INCH && c < INTER) ? dw2[(oc * INTER + c) * TLEN + m] : 0.0f;
            w2D[gid] = (short)f2bf(v);
        } else if (gid < 341504) {                           // w1D
            int idx = gid - 309760;
            int j = idx & 7, lane = (idx >> 3) & 63;
            int rest = idx >> 9;                             // st*2 + octile
            int ot = rest & 1, st = rest >> 1;
            int oc = ot * 16 + (lane & 15);
            int m  = st * 4 + (lane >> 4);
            float v = (oc < INTER && m < TLEN) ? dw1[(oc * EMB + j) * TLEN + m] : 0.0f;
            w1D[idx] = (short)f2bf(v);
        }
        return;
    }
    // ---- signal part ----
    const int blk = blockIdx.x;          // (b*8 + e)*3 + uc
    const int uc = blk % 3;
    const int be = blk / 3;
    const int b = be >> 3, e = be & 7;
    __shared__ float sp[FULL], sf[FULL], sa[FULL], sb[FULL];
    for (int nn = tid; nn < FULL; nn += 256) {
        int gi = (b * FULL + nn) * 8 + e;
        sp[nn] = pP[gi]; sf[nn] = pF[gi]; sa[nn] = pA[gi]; sb[nn] = pB[gi];
    }
    __syncthreads();
    if (tid < 240) {
        const int u = uc * 120 + (tid >> 1);
        const int half = tid & 1;
        int nlo = (u - 120 > 0) ? (u - 120) : 0;
        int nhi = (u < 239) ? u : 239;
        int mid = (nlo + nhi + 1) >> 1;
        int lo = half ? mid : nlo;
        int hi = half ? nhi : (mid - 1);
        float s = 0.0f;
        for (int nn = lo; nn <= hi; ++nn) {
            float tt = (float)(u - nn);
            float z = sf[nn] * (tt * (1.0f / 60.0f) - 1.0f) + sp[nn];
            z -= floorf(z);
            s += sa[nn] * __builtin_amdgcn_sinf(z) + sb[nn];   // v_sin_f32 (rev)
        }
        s += __shfl_xor(s, 1);
        if (half == 0) {
            float wgt = (u < TLEN) ? (float)(u + 1) : ((u > 239) ? (float)(LP - u) : 121.0f);
            float val = s / wgt;
            sig[(b * EMB + e) * LP + u] = val;
            if (u < TLEN) oSig[(b * EMB + e) * TLEN + u] = val;
        }
    }
}

// ---------------------------------------------------------------------------
// k_dec1: decoder conv1 via MFMA. Block = (b, shalf) = 32 blocks. (round 15)
// ---------------------------------------------------------------------------
__global__ __launch_bounds__(256) void k_dec1(
    const float* __restrict__ sig, const short* __restrict__ w1D, const float* __restrict__ db1,
    float* __restrict__ dbuf, float* __restrict__ bns)
{
    const int blk = blockIdx.x;            // b*2 + shalf
    const int shalf = blk & 1, b = blk >> 1;
    const int tid = threadIdx.x;
    const int lane = tid & 63, wid = tid >> 6;
    __shared__ __align__(16) short yT[256 * 8];      // 4096 B (rows 248..255 stay 0)
    __shared__ float sS[INTER], sS2[INTER];

    if (tid < 256) ((uint4*)yT)[tid] = make_uint4(0, 0, 0, 0);
    if (tid < INTER) { sS[tid] = 0.0f; sS2[tid] = 0.0f; }
    __syncthreads();
    const int qbase = shalf * 120 - 60;
    for (int idx = tid; idx < 248 * 8; idx += 256) {
        int c = idx / 248, pos = idx - c * 248;
        int qy = qbase + pos;
        if (qy >= 0 && qy < FULL)
            yT[pos * 8 + c] = (short)f2bf(sig[(b * EMB + c) * LP + qy + 60]);
    }
    __syncthreads();

    const int col = lane & 15, quad = lane >> 4;
    f32x4 aA0 = {0,0,0,0}, aA1 = {0,0,0,0};   // stile wid   x octile 0/1
    f32x4 aB0 = {0,0,0,0}, aB1 = {0,0,0,0};   // stile wid+4 x octile 0/1
    const short* bb0 = yT + (wid * 16 + col + quad) * 8;
    const short* bb1 = yT + ((wid + 4) * 16 + col + quad) * 8;
#pragma unroll 4
    for (int st = 0; st < 31; ++st) {
        s16x8 a0 = *(const s16x8*)(w1D + ((st * 2 + 0) * 64 + lane) * 8);
        s16x8 a1 = *(const s16x8*)(w1D + ((st * 2 + 1) * 64 + lane) * 8);
        s16x8 b0 = *(const s16x8*)(bb0 + st * 32);
        s16x8 b1 = *(const s16x8*)(bb1 + st * 32);
        aA0 = __builtin_amdgcn_mfma_f32_16x16x32_bf16(a0, b0, aA0, 0, 0, 0);
        aA1 = __builtin_amdgcn_mfma_f32_16x16x32_bf16(a1, b0, aA1, 0, 0, 0);
        aB0 = __builtin_amdgcn_mfma_f32_16x16x32_bf16(a0, b1, aB0, 0, 0, 0);
        aB1 = __builtin_amdgcn_mfma_f32_16x16x32_bf16(a1, b1, aB1, 0, 0, 0);
    }

    // epilogue: bias + store dbuf + masked stats (col-reduce then LDS atomics)
#pragma unroll
    for (int half = 0; half < 2; ++half) {
        const int sl_base = (wid + half * 4) * 16;
#pragma unroll
        for (int ot = 0; ot < 2; ++ot) {
            f32x4 acc = (half == 0) ? (ot == 0 ? aA0 : aA1) : (ot == 0 ? aB0 : aB1);
#pragma unroll
            for (int r = 0; r < 4; ++r) {
                int oc = ot * 16 + quad * 4 + r;
                int sl = sl_base + col;
                float val = 0.0f;
                if (oc < INTER && sl < 120) {
                    val = acc[r] + db1[oc];
                    dbuf[(b * INTER + oc) * FULL + shalf * 120 + sl] = val;
                }
                float s1 = val, s2 = val * val;
                s1 += __shfl_xor(s1, 1); s2 += __shfl_xor(s2, 1);
                s1 += __shfl_xor(s1, 2); s2 += __shfl_xor(s2, 2);
                s1 += __shfl_xor(s1, 4); s2 += __shfl_xor(s2, 4);
                s1 += __shfl_xor(s1, 8); s2 += __shfl_xor(s2, 8);
                if (col == 0 && oc < INTER) {
                    atomicAdd(&sS[oc], s1);
                    atomicAdd(&sS2[oc], s2);
                }
            }
        }
    }
    __syncthreads();
    if (tid < INTER) {
        atomicAdd(&bns[tid], sS[tid]);
        atomicAdd(&bns[24 + tid], sS2[tid]);
    }
}

// ---------------------------------------------------------------------------
// k_dec2: decoder conv2 via MFMA with fused BN+tanh staging. (round 15 +
// round 27: fast_tanh)
// ---------------------------------------------------------------------------
__global__ __launch_bounds__(256) void k_dec2(
    const float* __restrict__ dbuf, const float* __restrict__ bns,
    const float* __restrict__ gma, const float* __restrict__ bta,
    const short* __restrict__ w2D, const float* __restrict__ db2,
    float* __restrict__ oY, float* __restrict__ oYp)
{
    const int blk = blockIdx.x;            // (b*2 + shalf)*5 + octile
    const int octile = blk % 5;
    const int bh = blk / 5;
    const int shalf = bh & 1, b = bh >> 1;
    const int tid = threadIdx.x;
    const int lane = tid & 63, wid = tid >> 6;
    __shared__ __align__(16) short dT[248 * 40];     // 19840 B
    __shared__ float scl[INTER], sft[INTER];

    if (tid < INTER) {
        float m  = bns[tid] * (1.0f / 3840.0f);
        float v  = bns[24 + tid] * (1.0f / 3840.0f) - m * m;
        float rs = rsqrtf(fmaxf(v, 0.0f) + 1e-5f);
        float g  = gma[tid];
        scl[tid] = rs * g;
        sft[tid] = bta[tid] - m * rs * g;
    }
    for (int idx = tid; idx < 1240; idx += 256) ((uint4*)dT)[idx] = make_uint4(0,0,0,0);
    __syncthreads();
    const int qbase = shalf * 120 - 60;
    for (int idx = tid; idx < 248 * 24; idx += 256) {
        int c = idx / 248, pos = idx - c * 248;
        int qy = qbase + pos;
        if (qy >= 0 && qy < FULL) {
            float v = fast_tanh(dbuf[(b * INTER + c) * FULL + qy] * scl[c] + sft[c]);
            dT[pos * 40 + c] = (short)f2bf(v);
        }
    }
    __syncthreads();

    const int col = lane & 15, quad = lane >> 4;
    f32x4 acc0 = {0,0,0,0}, acc1 = {0,0,0,0};
    const short* bb0 = dT + (wid * 16 + col) * 40 + quad * 8;
    const short* bb1 = dT + ((wid + 4) * 16 + col) * 40 + quad * 8;
    const short* ab  = w2D + (octile * 64 + lane) * 8;
#pragma unroll 8
    for (int m = 0; m < TLEN; ++m) {
        s16x8 af = *(const s16x8*)(ab + m * 2560);       // 5*512 shorts per tap
        s16x8 b0 = *(const s16x8*)(bb0 + m * 40);
        s16x8 b1 = *(const s16x8*)(bb1 + m * 40);
        acc0 = __builtin_amdgcn_mfma_f32_16x16x32_bf16(af, b0, acc0, 0, 0, 0);
        acc1 = __builtin_amdgcn_mfma_f32_16x16x32_bf16(af, b1, acc1, 0, 0, 0);
    }

#pragma unroll
    for (int r = 0; r < 4; ++r) {
        int oc = octile * 16 + quad * 4 + r;
        if (oc < INCH) {
            float bias = db2[oc];
            {
                int sl = wid * 16 + col;                 // <= 63, always valid
                int sg = shalf * 120 + sl;
                float v = acc0[r] + bias;
                oY[(b * INCH + oc) * FULL + sg] = v;
                if (sg < TLEN) oYp[(b * INCH + oc) * TLEN + sg] = v;
            }
            {
                int sl = (wid + 4) * 16 + col;
                if (sl < 120) {
                    int sg = shalf * 120 + sl;
                    float v = acc1[r] + bias;
                    oY[(b * INCH + oc) * FULL + sg] = v;
                    if (sg < TLEN) oYp[(b * INCH + oc) * TLEN + sg] = v;
                }
            }
        }
    }
}

// ---------------------------------------------------------------------------
extern "C" void kernel_launch(void* const* d_in, const int* in_sizes, int n_in,
                              void* d_out, int out_size, void* d_ws, size_t ws_size,
                              hipStream_t stream)
{
    const float* x   = (const float*)d_in[0];
    const float* w1  = (const float*)d_in[1];
    const float* b1  = (const float*)d_in[2];
    const float* lna = (const float*)d_in[3];
    const float* lnb = (const float*)d_in[4];
    const float* w2  = (const float*)d_in[5];
    const float* b2  = (const float*)d_in[6];
    const float* fcw = (const float*)d_in[7];
    const float* fcb = (const float*)d_in[8];
    const float* dw1 = (const float*)d_in[9];
    const float* db1 = (const float*)d_in[10];
    const float* gma = (const float*)d_in[11];
    const float* bta = (const float*)d_in[12];
    const float* dw2 = (const float*)d_in[13];
    const float* db2 = (const float*)d_in[14];

    // Output layout (flat fp32, reference return order):
    float* out  = (float*)d_out;
    float* oY   = out;                 // [16][72][240]
    float* oLat = out + 276480;        // [16][8][121]
    float* oSig = out + 291968;        // [16][8][121]
    float* oP   = out + 307456;
    float* oF   = out + 307584;
    float* oA   = out + 307712;
    float* oB   = out + 307840;
    float* oYp  = out + 307968;        // [16][72][121]

    // Workspace layout (bytes): unchanged from round 22/25.
    short* w2f  = (short*)d_ws;
    short* w3f  = (short*)((char*)d_ws + 123904);
    short* w1fA = (short*)((char*)d_ws + 156672);
    float* fb   = (float*)((char*)d_ws + 900096);
    float* pP   = fb;
    float* pF   = pP + 30720;
    float* pA   = pF + 30720;
    float* pB   = pA + 30720;
    float* dbuf = fb;                  // overlay (temporally disjoint)
    float* sig  = fb + 122880;         // 46080
    float* bns  = sig + 46080;         // 48
    float* Q    = (float*)((char*)d_ws + 1576128);
    short* w2D  = (short*)((char*)d_ws + 1576128);            // Q overlay
    short* w1D  = (short*)((char*)d_ws + 1576128 + 619520);   // Q overlay

    k_prep_all<<<1644, 256, 0, stream>>>(w2, w1, w2f, w3f, w1fA, bns);
    k_q<<<512, 256, 0, stream>>>(x, w1fA, Q);
    k_prefix_ln<<<384, 256, 0, stream>>>(Q, b1, lna, lnb);
    k_enc2<<<1920, 256, 0, stream>>>(Q, w2f, w3f, b2, fcw, fcb,
                                     pP, pF, pA, pB, oLat, oP, oF, oA, oB);
    k_sig_prep<<<1718, 256, 0, stream>>>(pP, pF, pA, pB, sig, oSig,
                                         dw1, dw2, w1D, w2D);
    k_dec1<<<32, 256, 0, stream>>>(sig, w1D, db1, dbuf, bns);
    k_dec2<<<160, 256, 0, stream>>>(dbuf, bns, gma, bta, w2D, db2, oY, oYp);
}